// Round 1
// baseline (289.852 us; speedup 1.0000x reference)
//
#include <hip/hip_runtime.h>

typedef __attribute__((ext_vector_type(8))) short bf16x8;
typedef __attribute__((ext_vector_type(4))) short bf16x4;
typedef __attribute__((ext_vector_type(4))) float f32x4;

#define L2E 1.44269504088896340736f
#define QSCL 0.18033688011112042f   // 0.125 * log2(e)

__device__ inline unsigned short f2bf(float f) {
  union { float f; unsigned int u; } x; x.f = f;
  return (unsigned short)((x.u + 0x8000u) >> 16);
}
__device__ inline unsigned int f2bf2(float a, float b) {
  union { float f; unsigned int u; } xa, xb;
  xa.f = a; xb.f = b;
  return ((xa.u + 0x8000u) >> 16) | (((xb.u + 0x8000u) & 0xFFFF0000u));
}
// HW packed f32->bf16x2 (gfx950 v_cvt_pk_bf16_f32), compile-safe fallback.
__device__ inline unsigned int pk_bf16(float a, float b) {
#if __has_builtin(__builtin_amdgcn_cvt_pk_bf16_f32)
  typedef __attribute__((ext_vector_type(2))) __bf16 bfv2;
  union { bfv2 v; unsigned int u; } x;
  x.v = __builtin_amdgcn_cvt_pk_bf16_f32(a, b);
  return x.u;
#else
  return f2bf2(a, b);
#endif
}

__device__ inline void gl_lds16(const void* g, void* l) {
  __builtin_amdgcn_global_load_lds((const __attribute__((address_space(1))) void*)g,
                                   (__attribute__((address_space(3))) void*)l,
                                   16, 0, 0);
}

// Full drain (attn): compiler emits NO vmcnt before s_barrier here (R4 race
// proved it) — so the wait is entirely ours to specify.
__device__ inline void vm_drain() {
  asm volatile("s_waitcnt vmcnt(0)" ::: "memory");
}
// Counted waits: keep the newest prefetches in flight across barriers.
__device__ inline void vm_wait4() {
  asm volatile("s_waitcnt vmcnt(4)" ::: "memory");
}
__device__ inline void vm_wait3() {   // gemm_out: 3 gl_lds per tile
  asm volatile("s_waitcnt vmcnt(3)" ::: "memory");
}

// ---------------- fused cast fp32 -> bf16 (x, W_qkv, W_out) ----------------
#define N4_X  2097152   // 8192*1024/4
#define N4_WQ 786432    // 3072*1024/4
#define N4_WO 262144    // 1024*1024/4
__global__ void cast3_kernel(const float* __restrict__ x,
                             const float* __restrict__ wq,
                             const float* __restrict__ wo,
                             unsigned short* __restrict__ xb,
                             unsigned short* __restrict__ wqb,
                             unsigned short* __restrict__ wob) {
  int i = blockIdx.x * blockDim.x + threadIdx.x;
  int st = gridDim.x * blockDim.x;
  for (; i < N4_X + N4_WQ + N4_WO; i += st) {
    const float* src; unsigned short* dst; int j;
    if (i < N4_X)            { src = x;  dst = xb;  j = i; }
    else if (i < N4_X + N4_WQ){ src = wq; dst = wqb; j = i - N4_X; }
    else                     { src = wo; dst = wob; j = i - N4_X - N4_WQ; }
    float4 v = reinterpret_cast<const float4*>(src)[j];
    ushort4 o;
    o.x = f2bf(v.x); o.y = f2bf(v.y); o.z = f2bf(v.z); o.w = f2bf(v.w);
    reinterpret_cast<ushort4*>(dst)[j] = o;
  }
}

// ---------------- QKV GEMM v2: 256x256xBK64, 8 waves, 4-phase quadrant schedule --
// T2+T3+T4+T5 stack (m201 template adapted). Per-wave output 128x64 => 87
// FLOP per LDS byte (2.7x the old 128^2 structure's 32), so the 128 B/clk LDS
// read path no longer gates MFMA issue. Phases rotate acc quadrants
// [mlo,nlo]->[mlo,nhi]->[mhi,nlo]->[mhi,nhi] so consecutive phases share no
// accumulator: phase p's MFMA pipe drains under phase p+1's ds_reads.
// Staging: A(t+1) dist-1 into the idle buffer (P0/P1); B(t+2) dist-2 into the
// LIVE buffer in P2/P3 — safe because B-half0/1 are last ds_read in P1 and the
// per-phase double barrier lockstep orders every wave's reads before the issue.
// One counted vmcnt(4) per K-tile (end of P3): retires A(t+1)+older, leaves
// the 4 newest B(t+2) loads in flight across the barrier. Drain only at t=14.
// LDS layout: [256][64] bf16 per operand per buffer, chunk-XOR swizzle
// phys_chunk = logical_chunk ^ (row&7) via pre-swizzled global source (m173):
// ds_read_b128 then has 8 lanes per 4-bank group = free (b128 is >=8 clocks).
template <int MODE>
__device__ __forceinline__ void qkv_body(
    unsigned short* lds,
    const unsigned short* __restrict__ A,
    const unsigned short* __restrict__ Bm,
    unsigned short* __restrict__ qo,
    unsigned short* __restrict__ ko,
    unsigned short* __restrict__ vo,
    int tm, int tn) {
  const int tid = threadIdx.x;
  const int w = tid >> 6, lane = tid & 63;
  const int l15 = lane & 15, quad = lane >> 4;
  const int wmb = (w >> 2) * 128;     // wave A-row base within 256 tile
  const int wnb = (w & 3) * 64;       // wave B-row base
  const int rl = (w << 3) + (lane >> 3);                    // staging row 0..63
  const int scol = ((lane & 7) ^ ((lane >> 3) & 7)) << 3;   // pre-swizzled chunk
  const int rk = l15 & 7;                                   // read swizzle key

  const unsigned short* Ab = A + (size_t)(tm * 256) * 1024;
  const unsigned short* Bb = Bm + (size_t)(tn * 256) * 1024;

  unsigned short* sA0 = lds;            // 16384 shorts each
  unsigned short* sA1 = lds + 16384;
  unsigned short* sB0 = lds + 32768;
  unsigned short* sB1 = lds + 49152;

#define STG_HALF(Gb, R0, k0, Lb)                                              \
  do {                                                                        \
    gl_lds16((Gb) + (size_t)((R0) + rl) * 1024 + (k0) + scol,                 \
             (Lb) + ((R0) + (w << 3)) * 64);                                  \
    gl_lds16((Gb) + (size_t)((R0) + 64 + rl) * 1024 + (k0) + scol,            \
             (Lb) + ((R0) + 64 + (w << 3)) * 64);                             \
  } while (0)

#define LDF(buf, row, kk) \
  (*(const bf16x8*)&(buf)[(row) * 64 + ((((kk) * 4 + quad) ^ rk) << 3)])

  // prologue: tile0 A+B -> buf0; tile1 B -> buf1 (12 loads; wait first 8)
  STG_HALF(Ab, 0, 0, sA0);
  STG_HALF(Ab, 128, 0, sA0);
  STG_HALF(Bb, 0, 0, sB0);
  STG_HALF(Bb, 128, 0, sB0);
  STG_HALF(Bb, 0, 64, sB1);
  STG_HALF(Bb, 128, 64, sB1);

  const f32x4 fz = {0.f, 0.f, 0.f, 0.f};
  f32x4 acc[8][4];
#pragma unroll
  for (int i = 0; i < 8; i++)
#pragma unroll
    for (int j = 0; j < 4; j++) acc[i][j] = fz;

  vm_wait4();
  __syncthreads();

  for (int t = 0; t < 16; ++t) {
    unsigned short* Ac = (t & 1) ? sA1 : sA0;
    unsigned short* An = (t & 1) ? sA0 : sA1;   // A(t+1) target (idle buffer)
    unsigned short* Bc = (t & 1) ? sB1 : sB0;   // current B; also B(t+2) target
    bf16x8 a0[4][2], a1[4][2], b0[2][2], b1[2][2];

    // ---- P0: read a0(m-lo)+b0(n-lo); stage A-half0(t+1); MFMA [m-lo, n-lo]
#pragma unroll
    for (int mt = 0; mt < 4; mt++)
#pragma unroll
      for (int kk = 0; kk < 2; kk++)
        a0[mt][kk] = LDF(Ac, wmb + mt * 16 + l15, kk);
#pragma unroll
    for (int nt = 0; nt < 2; nt++)
#pragma unroll
      for (int kk = 0; kk < 2; kk++)
        b0[nt][kk] = LDF(Bc, wnb + nt * 16 + l15, kk);
    if (t < 15) STG_HALF(Ab, 0, (t + 1) << 6, An);
    __syncthreads();
    __builtin_amdgcn_s_setprio(1);
#pragma unroll
    for (int mt = 0; mt < 4; mt++)
#pragma unroll
      for (int nt = 0; nt < 2; nt++)
#pragma unroll
        for (int kk = 0; kk < 2; kk++)
          acc[mt][nt] = (MODE == 0)
            ? __builtin_amdgcn_mfma_f32_16x16x32_bf16(b0[nt][kk], a0[mt][kk], acc[mt][nt], 0, 0, 0)
            : __builtin_amdgcn_mfma_f32_16x16x32_bf16(a0[mt][kk], b0[nt][kk], acc[mt][nt], 0, 0, 0);
    __builtin_amdgcn_s_setprio(0);
    __syncthreads();

    // ---- P1: read b1(n-hi); stage A-half1(t+1); MFMA [m-lo, n-hi]
#pragma unroll
    for (int nt = 0; nt < 2; nt++)
#pragma unroll
      for (int kk = 0; kk < 2; kk++)
        b1[nt][kk] = LDF(Bc, wnb + (nt + 2) * 16 + l15, kk);
    if (t < 15) STG_HALF(Ab, 128, (t + 1) << 6, An);
    __syncthreads();
    __builtin_amdgcn_s_setprio(1);
#pragma unroll
    for (int mt = 0; mt < 4; mt++)
#pragma unroll
      for (int nt = 0; nt < 2; nt++)
#pragma unroll
        for (int kk = 0; kk < 2; kk++)
          acc[mt][nt + 2] = (MODE == 0)
            ? __builtin_amdgcn_mfma_f32_16x16x32_bf16(b1[nt][kk], a0[mt][kk], acc[mt][nt + 2], 0, 0, 0)
            : __builtin_amdgcn_mfma_f32_16x16x32_bf16(a0[mt][kk], b1[nt][kk], acc[mt][nt + 2], 0, 0, 0);
    __builtin_amdgcn_s_setprio(0);
    __syncthreads();

    // ---- P2: read a1(m-hi); stage B-half0(t+2) into live buffer (B-half0's
    //          last read was P1; barrier lockstep makes the overwrite safe);
    //          MFMA [m-hi, n-lo]
#pragma unroll
    for (int mt = 0; mt < 4; mt++)
#pragma unroll
      for (int kk = 0; kk < 2; kk++)
        a1[mt][kk] = LDF(Ac, wmb + (mt + 4) * 16 + l15, kk);
    if (t < 14) STG_HALF(Bb, 0, (t + 2) << 6, Bc);
    __syncthreads();
    __builtin_amdgcn_s_setprio(1);
#pragma unroll
    for (int mt = 0; mt < 4; mt++)
#pragma unroll
      for (int nt = 0; nt < 2; nt++)
#pragma unroll
        for (int kk = 0; kk < 2; kk++)
          acc[mt + 4][nt] = (MODE == 0)
            ? __builtin_amdgcn_mfma_f32_16x16x32_bf16(b0[nt][kk], a1[mt][kk], acc[mt + 4][nt], 0, 0, 0)
            : __builtin_amdgcn_mfma_f32_16x16x32_bf16(a1[mt][kk], b0[nt][kk], acc[mt + 4][nt], 0, 0, 0);
    __builtin_amdgcn_s_setprio(0);
    __syncthreads();

    // ---- P3: stage B-half1(t+2); MFMA [m-hi, n-hi]; counted vmcnt; barrier
    if (t < 14) STG_HALF(Bb, 128, (t + 2) << 6, Bc);
    __syncthreads();
    __builtin_amdgcn_s_setprio(1);
#pragma unroll
    for (int mt = 0; mt < 4; mt++)
#pragma unroll
      for (int nt = 0; nt < 2; nt++)
#pragma unroll
        for (int kk = 0; kk < 2; kk++)
          acc[mt + 4][nt + 2] = (MODE == 0)
            ? __builtin_amdgcn_mfma_f32_16x16x32_bf16(b1[nt][kk], a1[mt][kk], acc[mt + 4][nt + 2], 0, 0, 0)
            : __builtin_amdgcn_mfma_f32_16x16x32_bf16(a1[mt][kk], b1[nt][kk], acc[mt + 4][nt + 2], 0, 0, 0);
    __builtin_amdgcn_s_setprio(0);
    // retire A(t+1) (and everything older); keep newest 4 (B(t+2)) in flight.
    if (t < 14) vm_wait4();
    else if (t == 14) vm_drain();
    __syncthreads();
  }
#undef STG_HALF
#undef LDF

  // epilogue — same per-mode layouts as v1, wave geometry updated.
  const int bb = tm >> 2;
  const int n0 = (tm & 3) << 8;
  const int cb = (tn & 3) << 8;
  if (MODE == 0) {
    const float scl = (tn < 4) ? QSCL : 1.0f;
    unsigned short* dst = (tn < 4) ? qo : ko;
#pragma unroll
    for (int mt = 0; mt < 8; mt++) {
      int tok = n0 + wmb + mt * 16 + l15;
#pragma unroll
      for (int nt = 0; nt < 4; nt++) {
        int c = cb + wnb + nt * 16 + quad * 4;
        int hh = c >> 6, d0 = c & 63;
        uint2 val;
        val.x = f2bf2(acc[mt][nt][0] * scl, acc[mt][nt][1] * scl);
        val.y = f2bf2(acc[mt][nt][2] * scl, acc[mt][nt][3] * scl);
        *(uint2*)&dst[(((size_t)bb * 16 + hh) * 1024 + tok) * 64 + d0] = val;
      }
    }
  } else {
#pragma unroll
    for (int mt = 0; mt < 8; mt++) {
      int tok = n0 + wmb + mt * 16 + quad * 4;
#pragma unroll
      for (int nt = 0; nt < 4; nt++) {
        int c = cb + wnb + nt * 16 + l15;
        int hh = c >> 6, dd = c & 63;
        uint2 val;
        val.x = f2bf2(acc[mt][nt][0], acc[mt][nt][1]);
        val.y = f2bf2(acc[mt][nt][2], acc[mt][nt][3]);
        *(uint2*)&vo[(((size_t)bb * 16 + hh) * 64 + dd) * 1024 + tok] = val;
      }
    }
  }
}

// grid 384 = 32(tm) x 12(tn), flattened; 384%8==0 so the simple bijective
// XCD swizzle applies (each XCD gets 48 consecutive wg = 4 A-panels).
__global__ __launch_bounds__(512, 2) void gemm_qkv(
    const unsigned short* __restrict__ A,
    const unsigned short* __restrict__ Bm,
    unsigned short* __restrict__ qo,
    unsigned short* __restrict__ ko,
    unsigned short* __restrict__ vo) {
  __shared__ unsigned short lds[65536];   // 128 KiB: A dbuf + B dbuf
  const int id = blockIdx.x;
  const int wg = (id & 7) * 48 + (id >> 3);
  const int tm = wg / 12, tn = wg - tm * 12;
  if (tn < 8) qkv_body<0>(lds, A, Bm, qo, ko, vo, tm, tn);
  else        qkv_body<1>(lds, A, Bm, qo, ko, vo, tm, tn);
}

// ---------------- flash attention: S^T, register PV, reflected-bias, MFMA rsum ----
__global__ __launch_bounds__(256, 2) void attn_kernel(
    const unsigned short* __restrict__ Q,
    const unsigned short* __restrict__ Kg,
    const unsigned short* __restrict__ Vt,
    const float* __restrict__ biases,
    unsigned short* __restrict__ Og) {
  __shared__ unsigned short sK[2][64 * 64];
  __shared__ unsigned short sV[2][64 * 64];   // [d][kv], 16B-chunk XOR-swizzled
  __shared__ float sBias2[32 * 63];           // reflected: [di][31 + (qj-kvj)]

  const int bx = blockIdx.x;
  const int bh = bx & 127, qt = bx >> 7;      // qt 0..3; same bh -> same XCD
  const int h = bh & 15, b = bh >> 4;
  const int tid = threadIdx.x, w = tid >> 6, lane = tid & 63;
  const int l15 = lane & 15, quad = lane >> 4;

  const size_t bhs = (size_t)(b * 16 + h);
  const unsigned short* qbase = Q + (bhs * 1024 + (size_t)qt * 256) * 64;
  const unsigned short* kbase = Kg + bhs * 1024 * 64;
  const unsigned short* vbase = Vt + bhs * 64 * 1024;

  for (int t = tid; t < 2048; t += 256) {
    int d = t >> 6, u = t & 63;
    if (u < 63) {
      int dj = u - 31; dj = dj < 0 ? -dj : dj;
      sBias2[d * 63 + u] = biases[h * 1024 + d * 32 + dj] * L2E;
    }
  }

  const int sr0 = w * 16 + (lane >> 3);
  const int sc8 = lane & 7;
  const int sw0 = sc8 ^ (lane >> 3);

  gl_lds16(kbase + (size_t)sr0 * 64 + sw0 * 8,        &sK[0][(w * 16) * 64]);
  gl_lds16(kbase + (size_t)(sr0 + 8) * 64 + sw0 * 8,  &sK[0][(w * 16 + 8) * 64]);
  gl_lds16(vbase + (size_t)sr0 * 1024 + sw0 * 8,      &sV[0][(w * 16) * 64]);
  gl_lds16(vbase + (size_t)(sr0 + 8) * 1024 + sw0 * 8,&sV[0][(w * 16 + 8) * 64]);

  bf16x8 qf[4][2];
#pragma unroll
  for (int qb = 0; qb < 4; qb++)
#pragma unroll
    for (int kd = 0; kd < 2; kd++)
      qf[qb][kd] = *(const bf16x8*)(qbase + (w * 64 + qb * 16 + l15) * 64 + kd * 32 + quad * 8);

  const int qg0 = qt * 256 + w * 64;
  const int qtw = __builtin_amdgcn_readfirstlane(qt * 8 + w * 2);
  int cc2[2][2];
#pragma unroll
  for (int qh = 0; qh < 2; qh++)
#pragma unroll
    for (int kp = 0; kp < 2; kp++)
      cc2[qh][kp] = qh * 16 + l15 - kp * 16 - quad * 4;

  const f32x4 fz = {0.f, 0.f, 0.f, 0.f};
  f32x4 of[4][4], osum[4];
#pragma unroll
  for (int i = 0; i < 4; i++) {
    osum[i] = fz;
#pragma unroll
    for (int j = 0; j < 4; j++) of[i][j] = fz;
  }
  const bf16x4 vones = {(short)0x3F80, (short)0x3F80, (short)0x3F80, (short)0x3F80};

  int buf = 0;
  for (int j0 = 0; j0 < 1024; j0 += 64) {
    vm_drain();
    __syncthreads();
    if (j0 + 64 < 1024) {
      int nb = buf ^ 1, jn = j0 + 64;
      gl_lds16(kbase + (size_t)(jn + sr0) * 64 + sw0 * 8,       &sK[nb][(w * 16) * 64]);
      gl_lds16(kbase + (size_t)(jn + sr0 + 8) * 64 + sw0 * 8,   &sK[nb][(w * 16 + 8) * 64]);
      gl_lds16(vbase + (size_t)sr0 * 1024 + jn + sw0 * 8,       &sV[nb][(w * 16) * 64]);
      gl_lds16(vbase + (size_t)(sr0 + 8) * 1024 + jn + sw0 * 8, &sV[nb][(w * 16 + 8) * 64]);
    }
    const unsigned short* K_ = sK[buf];
    const unsigned short* V_ = sV[buf];
    const int j5 = j0 >> 5;
    const int dh = qtw - j5;                  // qi(qb) = qtw + (qb>>1)
    const float* b0 = sBias2 + abs(dh) * 63 + 31;       // (qb>>1) == (kvb>>1)
    const float* bM = sBias2 + abs(dh - 1) * 63 + 31;   // qb<2, kvb>=2
    const float* bP = sBias2 + abs(dh + 1) * 63 + 31;   // qb>=2, kvb<2

#pragma unroll
    for (int kvb = 0; kvb < 4; kvb++) {
      bf16x8 kf0 = *(const bf16x8*)&K_[(kvb * 16 + l15) * 64 + ((quad ^ (l15 & 7)) << 3)];
      bf16x8 kf1 = *(const bf16x8*)&K_[(kvb * 16 + l15) * 64 + (((4 + quad) ^ (l15 & 7)) << 3)];
      bf16x4 vf[4];
#pragma unroll
      for (int nt = 0; nt < 4; nt++) {
        int d = nt * 16 + l15;
        vf[nt] = *(const bf16x4*)&V_[d * 64 + (((kvb * 2 + (quad >> 1)) ^ (l15 & 7)) << 3) + (quad & 1) * 4];
      }
      const int kp = kvb & 1;
#pragma unroll
      for (int qb = 0; qb < 4; qb++) {
        f32x4 s4 = __builtin_amdgcn_mfma_f32_16x16x32_bf16(kf0, qf[qb][0], fz, 0, 0, 0);
        s4 = __builtin_amdgcn_mfma_f32_16x16x32_bf16(kf1, qf[qb][1], s4, 0, 0, 0);
        const float* bp = (qb < 2) ? ((kvb < 2) ? b0 : bM)
                                   : ((kvb < 2) ? bP : b0);
        const float* bq = bp + cc2[qb & 1][kp];   // bq[-r] = bias for kv=kvjb+r
        float p0 = __builtin_amdgcn_exp2f(s4.x + bq[0]);
        float p1 = __builtin_amdgcn_exp2f(s4.y + bq[-1]);
        float p2 = __builtin_amdgcn_exp2f(s4.z + bq[-2]);
        float p3 = __builtin_amdgcn_exp2f(s4.w + bq[-3]);
        union { unsigned int u[2]; bf16x4 v; } pk;
        pk.u[0] = pk_bf16(p0, p1);
        pk.u[1] = pk_bf16(p2, p3);
#pragma unroll
        for (int nt = 0; nt < 4; nt++)
          of[qb][nt] = __builtin_amdgcn_mfma_f32_16x16x16bf16_1k(pk.v, vf[nt], of[qb][nt], 0, 0, 0);
        osum[qb] = __builtin_amdgcn_mfma_f32_16x16x16bf16_1k(pk.v, vones, osum[qb], 0, 0, 0);
      }
    }
    buf ^= 1;
  }

  const int kvq = quad * 4;
#pragma unroll
  for (int qb = 0; qb < 4; qb++)
#pragma unroll
    for (int r = 0; r < 4; r++) {
      float inv = __builtin_amdgcn_rcpf(osum[qb][r]);   // same C-layout row as of
      int n = qg0 + qb * 16 + kvq + r;
      size_t orow = ((size_t)b * 1024 + n) * 1024 + h * 64;
#pragma unroll
      for (int nt = 0; nt < 4; nt++)
        Og[orow + nt * 16 + l15] = f2bf(of[qb][nt][r] * inv);
    }
}

// ---------------- out-proj GEMM: [8192,1024] x [1024,1024]^T + b ----------------
// R12: 128x64 tiles -> grid 16x64 = 1024 blocks = exactly 4/CU single balanced
// pass (the 128x128 grid was 512 blocks = 2/CU, grid-limited occupancy).
// LDS 36 KB = 3 stages x (8K A + 4K B); 3 gl_lds/tile -> vmcnt(3) partial wait.
__global__ __launch_bounds__(256, 4) void gemm_out_k(
    const unsigned short* __restrict__ A,
    const unsigned short* __restrict__ Bm,
    const float* __restrict__ bias,
    float* __restrict__ out) {
  __shared__ unsigned short sA[3][128 * 32];
  __shared__ unsigned short sB[3][64 * 32];
  const int K = 1024;
  const int tid = threadIdx.x;
  const int w = tid >> 6, lane = tid & 63;
  const int l15 = lane & 15, quad = lane >> 4;
  const int tm = blockIdx.y, tn = blockIdx.x;

  const unsigned short* Ab = A + (size_t)(tm * 128) * K;
  const unsigned short* Bb = Bm + (size_t)(tn * 64) * K;

  const int srowA = w * 32 + (lane >> 2);
  const int srowB = w * 16 + (lane >> 2);
  const int scol = (((lane & 3) ^ ((lane >> 3) & 3))) * 8;   // swizzled content chunk
  const int rsw = (l15 >> 1) & 3;                            // read-side swizzle key

  const f32x4 fz = {0.f, 0.f, 0.f, 0.f};
  f32x4 acc[2][4];
#pragma unroll
  for (int i = 0; i < 2; i++)
#pragma unroll
    for (int j = 0; j < 4; j++) acc[i][j] = fz;

#define OUT_STAGE(kn, nb)                                                          \
  do {                                                                             \
    gl_lds16(Ab + (size_t)srowA * K + (kn) + scol,        &sA[nb][(w * 32) * 32]);      \
    gl_lds16(Ab + (size_t)(srowA + 16) * K + (kn) + scol, &sA[nb][(w * 32 + 16) * 32]); \
    gl_lds16(Bb + (size_t)srowB * K + (kn) + scol,        &sB[nb][(w * 16) * 32]);      \
  } while (0)

  OUT_STAGE(0, 0);
  OUT_STAGE(32, 1);

  int bi = 0;
  for (int k0 = 0; k0 < K; k0 += 32) {
    if (k0 + 64 < K) vm_wait3(); else vm_drain();
    __syncthreads();
    if (k0 + 64 < K) {
      int nb = bi + 2; if (nb >= 3) nb -= 3;
      OUT_STAGE(k0 + 64, nb);
    }
    bf16x8 af[2], bfr[4];
#pragma unroll
    for (int mt = 0; mt < 2; mt++)
      af[mt] = *(const bf16x8*)&sA[bi][(w * 32 + mt * 16 + l15) * 32 + ((quad ^ rsw) << 3)];
#pragma unroll
    for (int nt = 0; nt < 4; nt++)
      bfr[nt] = *(const bf16x8*)&sB[bi][(nt * 16 + l15) * 32 + ((quad ^ rsw) << 3)];
#pragma unroll
    for (int mt = 0; mt < 2; mt++)
#pragma unroll
      for (int nt = 0; nt < 4; nt++)
        acc[mt][nt] = __builtin_amdgcn_mfma_f32_16x16x32_bf16(af[mt], bfr[nt], acc[mt][nt], 0, 0, 0);
    bi = bi + 1; if (bi == 3) bi = 0;
  }
#undef OUT_STAGE

  const int m0 = tm * 128 + w * 32, c0 = tn * 64;
#pragma unroll
  for (int mt = 0; mt < 2; mt++)
#pragma unroll
    for (int nt = 0; nt < 4; nt++)
#pragma unroll
      for (int r = 0; r < 4; r++) {
        int m = m0 + mt * 16 + quad * 4 + r;
        int c = c0 + nt * 16 + l15;
        out[(size_t)m * 1024 + c] = acc[mt][nt][r] + bias[c];
      }
}

extern "C" void kernel_launch(void* const* d_in, const int* in_sizes, int n_in,
                              void* d_out, int out_size, void* d_ws, size_t ws_size,
                              hipStream_t stream) {
  const float* x    = (const float*)d_in[0];
  const float* Wqkv = (const float*)d_in[1];
  const float* ab   = (const float*)d_in[2];
  // d_in[3] (bias_idxs) unused: idx == |n/32-m/32|*32 + |n%32-m%32| analytically
  const float* Wout = (const float*)d_in[4];
  const float* bout = (const float*)d_in[5];
  float* out = (float*)d_out;

  char* ws = (char*)d_ws;
  unsigned short* xb  = (unsigned short*)(ws);                    // 16 MB
  unsigned short* wqb = (unsigned short*)(ws + 16777216);         // 6 MB
  unsigned short* wob = (unsigned short*)(ws + 23068672);         // 2 MB
  unsigned short* qw  = (unsigned short*)(ws + 25165824);         // 16 MB
  unsigned short* kw  = (unsigned short*)(ws + 41943040);         // 16 MB
  unsigned short* vw  = (unsigned short*)(ws + 58720256);         // 16 MB (vT)
  unsigned short* ow  = (unsigned short*)(ws + 75497472);         // 16 MB

  cast3_kernel<<<1536, 256, 0, stream>>>(x, Wqkv, Wout, xb, wqb, wob);
  gemm_qkv<<<384, 512, 0, stream>>>(xb, wqb, qw, kw, vw);
  attn_kernel<<<512, 256, 0, stream>>>(qw, kw, vw, ab, ow);
  gemm_out_k<<<dim3(16, 64), 256, 0, stream>>>(ow, wob, bout, out);
}

// Round 2
// 256.838 us; speedup vs baseline: 1.1285x; 1.1285x over previous
//
#include <hip/hip_runtime.h>

typedef __attribute__((ext_vector_type(8))) short bf16x8;
typedef __attribute__((ext_vector_type(4))) short bf16x4;
typedef __attribute__((ext_vector_type(4))) float f32x4;

#define L2E 1.44269504088896340736f
#define QSCL 0.18033688011112042f   // 0.125 * log2(e)

__device__ inline unsigned short f2bf(float f) {
  union { float f; unsigned int u; } x; x.f = f;
  return (unsigned short)((x.u + 0x8000u) >> 16);
}
__device__ inline unsigned int f2bf2(float a, float b) {
  union { float f; unsigned int u; } xa, xb;
  xa.f = a; xb.f = b;
  return ((xa.u + 0x8000u) >> 16) | (((xb.u + 0x8000u) & 0xFFFF0000u));
}
// HW packed f32->bf16x2 (gfx950 v_cvt_pk_bf16_f32), compile-safe fallback.
__device__ inline unsigned int pk_bf16(float a, float b) {
#if __has_builtin(__builtin_amdgcn_cvt_pk_bf16_f32)
  typedef __attribute__((ext_vector_type(2))) __bf16 bfv2;
  union { bfv2 v; unsigned int u; } x;
  x.v = __builtin_amdgcn_cvt_pk_bf16_f32(a, b);
  return x.u;
#else
  return f2bf2(a, b);
#endif
}

__device__ inline void gl_lds16(const void* g, void* l) {
  __builtin_amdgcn_global_load_lds((const __attribute__((address_space(1))) void*)g,
                                   (__attribute__((address_space(3))) void*)l,
                                   16, 0, 0);
}

// Full drain (attn): compiler emits NO vmcnt before s_barrier here (R4 race
// proved it) — so the wait is entirely ours to specify.
__device__ inline void vm_drain() {
  asm volatile("s_waitcnt vmcnt(0)" ::: "memory");
}
__device__ inline void vm_wait3() {   // gemm_out: 3 gl_lds per tile
  asm volatile("s_waitcnt vmcnt(3)" ::: "memory");
}
__device__ inline void vm_wait8() {   // gemm_qkv v3: 8 gl_lds per K-tile
  asm volatile("s_waitcnt vmcnt(8)" ::: "memory");
}

// RAW barrier: NO implicit lgkmcnt(0)/vmcnt(0) drain (unlike __syncthreads,
// whose pre-barrier lgkmcnt(0) serialized the whole v2 schedule — R1 post-
// mortem). Memory-clobber asm fences stop the compiler moving LDS/VMEM ops
// across; HW waits are the compiler's fine-grained per-operand lgkmcnt plus
// our counted vmcnt.
__device__ inline void wave_barrier() {
  asm volatile("" ::: "memory");
  __builtin_amdgcn_s_barrier();
  asm volatile("" ::: "memory");
}

// ---------------- fused cast fp32 -> bf16 (x, W_qkv, W_out) ----------------
#define N4_X  2097152   // 8192*1024/4
#define N4_WQ 786432    // 3072*1024/4
#define N4_WO 262144    // 1024*1024/4
__global__ void cast3_kernel(const float* __restrict__ x,
                             const float* __restrict__ wq,
                             const float* __restrict__ wo,
                             unsigned short* __restrict__ xb,
                             unsigned short* __restrict__ wqb,
                             unsigned short* __restrict__ wob) {
  int i = blockIdx.x * blockDim.x + threadIdx.x;
  int st = gridDim.x * blockDim.x;
  for (; i < N4_X + N4_WQ + N4_WO; i += st) {
    const float* src; unsigned short* dst; int j;
    if (i < N4_X)            { src = x;  dst = xb;  j = i; }
    else if (i < N4_X + N4_WQ){ src = wq; dst = wqb; j = i - N4_X; }
    else                     { src = wo; dst = wob; j = i - N4_X - N4_WQ; }
    float4 v = reinterpret_cast<const float4*>(src)[j];
    ushort4 o;
    o.x = f2bf(v.x); o.y = f2bf(v.y); o.z = f2bf(v.z); o.w = f2bf(v.w);
    reinterpret_cast<ushort4*>(dst)[j] = o;
  }
}

// ---------------- QKV GEMM v3: 256x256xBK64, 8 waves, 4-phase, raw barriers --
// R1 post-mortem fixes vs v2:
//  (1) raw s_barrier (no pre-barrier lgkmcnt drain) -> wave-skew overlap of
//      LDS drain with MFMA restored (the v2 killer).
//  (2) slot-death-correct staging ring: per-wave read split means BOTH B
//      halves die after P1 and BOTH A halves die after P2. So: P2 stages the
//      FULL B(t+2) (4 gl_lds), P3 stages the FULL A(t+2) (4 gl_lds), both
//      into the LIVE buffer ((t+2)&1 == t&1), always after the last read of
//      the rows they overwrite (barrier-ordered).
//  (3) one counted vmcnt(8) per K-tile at end of P3: retires ALL of tile t+1
//      (read from P0 of t+1 on) while tile t+2's 8 loads stay in flight
//      across the barrier. Prefetch distance 5-6 phases >> HBM latency.
//      Never drains in the main loop; drain once at t==14.
// Phases rotate acc quadrants so consecutive phases share no accumulator.
template <int MODE>
__device__ __forceinline__ void qkv_body(
    unsigned short* lds,
    const unsigned short* __restrict__ A,
    const unsigned short* __restrict__ Bm,
    unsigned short* __restrict__ qo,
    unsigned short* __restrict__ ko,
    unsigned short* __restrict__ vo,
    int tm, int tn) {
  const int tid = threadIdx.x;
  const int w = tid >> 6, lane = tid & 63;
  const int l15 = lane & 15, quad = lane >> 4;
  const int wmb = (w >> 2) * 128;     // wave A-row base within 256 tile
  const int wnb = (w & 3) * 64;       // wave B-row base
  const int rl = (w << 3) + (lane >> 3);                    // staging row 0..63
  const int scol = ((lane & 7) ^ ((lane >> 3) & 7)) << 3;   // pre-swizzled chunk
  const int rk = l15 & 7;                                   // read swizzle key

  const unsigned short* Ab = A + (size_t)(tm * 256) * 1024;
  const unsigned short* Bb = Bm + (size_t)(tn * 256) * 1024;

  unsigned short* sA0 = lds;            // 16384 shorts each
  unsigned short* sA1 = lds + 16384;
  unsigned short* sB0 = lds + 32768;
  unsigned short* sB1 = lds + 49152;

#define STG_HALF(Gb, R0, k0, Lb)                                              \
  do {                                                                        \
    gl_lds16((Gb) + (size_t)((R0) + rl) * 1024 + (k0) + scol,                 \
             (Lb) + ((R0) + (w << 3)) * 64);                                  \
    gl_lds16((Gb) + (size_t)((R0) + 64 + rl) * 1024 + (k0) + scol,            \
             (Lb) + ((R0) + 64 + (w << 3)) * 64);                             \
  } while (0)

#define LDF(buf, row, kk) \
  (*(const bf16x8*)&(buf)[(row) * 64 + ((((kk) * 4 + quad) ^ rk) << 3)])

  // prologue: tiles 0 and 1 fully staged (16 gl_lds)
  STG_HALF(Ab, 0, 0, sA0);  STG_HALF(Ab, 128, 0, sA0);
  STG_HALF(Bb, 0, 0, sB0);  STG_HALF(Bb, 128, 0, sB0);
  STG_HALF(Ab, 0, 64, sA1); STG_HALF(Ab, 128, 64, sA1);
  STG_HALF(Bb, 0, 64, sB1); STG_HALF(Bb, 128, 64, sB1);

  const f32x4 fz = {0.f, 0.f, 0.f, 0.f};
  f32x4 acc[8][4];
#pragma unroll
  for (int i = 0; i < 8; i++)
#pragma unroll
    for (int j = 0; j < 4; j++) acc[i][j] = fz;

  vm_wait8();           // tile0 resident (tile1's 8 loads stay in flight)
  wave_barrier();

  for (int t = 0; t < 16; ++t) {
    unsigned short* Ac = (t & 1) ? sA1 : sA0;   // live buffers: read tile t,
    unsigned short* Bc = (t & 1) ? sB1 : sB0;   // and stage tile t+2 into them
    const int kf = (t + 2) << 6;
    bf16x8 a0[4][2], a1[4][2], b0[2][2], b1[2][2];

    // ---- P0: read a0(m-lo) + b0(n-lo); MFMA [m-lo, n-lo]
#pragma unroll
    for (int mt = 0; mt < 4; mt++)
#pragma unroll
      for (int kk = 0; kk < 2; kk++)
        a0[mt][kk] = LDF(Ac, wmb + mt * 16 + l15, kk);
#pragma unroll
    for (int nt = 0; nt < 2; nt++)
#pragma unroll
      for (int kk = 0; kk < 2; kk++)
        b0[nt][kk] = LDF(Bc, wnb + nt * 16 + l15, kk);
    wave_barrier();
    __builtin_amdgcn_s_setprio(1);
#pragma unroll
    for (int mt = 0; mt < 4; mt++)
#pragma unroll
      for (int nt = 0; nt < 2; nt++)
#pragma unroll
        for (int kk = 0; kk < 2; kk++)
          acc[mt][nt] = (MODE == 0)
            ? __builtin_amdgcn_mfma_f32_16x16x32_bf16(b0[nt][kk], a0[mt][kk], acc[mt][nt], 0, 0, 0)
            : __builtin_amdgcn_mfma_f32_16x16x32_bf16(a0[mt][kk], b0[nt][kk], acc[mt][nt], 0, 0, 0);
    __builtin_amdgcn_s_setprio(0);
    wave_barrier();

    // ---- P1: read b1(n-hi); MFMA [m-lo, n-hi]. After this phase BOTH B
    //          halves of tile t are dead (all waves' b0/b1 reads done).
#pragma unroll
    for (int nt = 0; nt < 2; nt++)
#pragma unroll
      for (int kk = 0; kk < 2; kk++)
        b1[nt][kk] = LDF(Bc, wnb + (nt + 2) * 16 + l15, kk);
    wave_barrier();
    __builtin_amdgcn_s_setprio(1);
#pragma unroll
    for (int mt = 0; mt < 4; mt++)
#pragma unroll
      for (int nt = 0; nt < 2; nt++)
#pragma unroll
        for (int kk = 0; kk < 2; kk++)
          acc[mt][nt + 2] = (MODE == 0)
            ? __builtin_amdgcn_mfma_f32_16x16x32_bf16(b1[nt][kk], a0[mt][kk], acc[mt][nt + 2], 0, 0, 0)
            : __builtin_amdgcn_mfma_f32_16x16x32_bf16(a0[mt][kk], b1[nt][kk], acc[mt][nt + 2], 0, 0, 0);
    __builtin_amdgcn_s_setprio(0);
    wave_barrier();

    // ---- P2: read a1(m-hi); stage FULL B(t+2) into live B buffer (B(t) rows
    //          died at P1; barrier-ordered). MFMA [m-hi, n-lo].
#pragma unroll
    for (int mt = 0; mt < 4; mt++)
#pragma unroll
      for (int kk = 0; kk < 2; kk++)
        a1[mt][kk] = LDF(Ac, wmb + (mt + 4) * 16 + l15, kk);
    if (t < 14) { STG_HALF(Bb, 0, kf, Bc); STG_HALF(Bb, 128, kf, Bc); }
    wave_barrier();
    __builtin_amdgcn_s_setprio(1);
#pragma unroll
    for (int mt = 0; mt < 4; mt++)
#pragma unroll
      for (int nt = 0; nt < 2; nt++)
#pragma unroll
        for (int kk = 0; kk < 2; kk++)
          acc[mt + 4][nt] = (MODE == 0)
            ? __builtin_amdgcn_mfma_f32_16x16x32_bf16(b0[nt][kk], a1[mt][kk], acc[mt + 4][nt], 0, 0, 0)
            : __builtin_amdgcn_mfma_f32_16x16x32_bf16(a1[mt][kk], b0[nt][kk], acc[mt + 4][nt], 0, 0, 0);
    __builtin_amdgcn_s_setprio(0);
    wave_barrier();

    // ---- P3: stage FULL A(t+2) (A(t) rows died at P2); MFMA [m-hi, n-hi];
    //          one counted vmcnt(8) per tile: retires all of tile t+1, keeps
    //          tile t+2's 8 loads in flight across the barrier.
    if (t < 14) { STG_HALF(Ab, 0, kf, Ac); STG_HALF(Ab, 128, kf, Ac); }
    wave_barrier();
    __builtin_amdgcn_s_setprio(1);
#pragma unroll
    for (int mt = 0; mt < 4; mt++)
#pragma unroll
      for (int nt = 0; nt < 2; nt++)
#pragma unroll
        for (int kk = 0; kk < 2; kk++)
          acc[mt + 4][nt + 2] = (MODE == 0)
            ? __builtin_amdgcn_mfma_f32_16x16x32_bf16(b1[nt][kk], a1[mt][kk], acc[mt + 4][nt + 2], 0, 0, 0)
            : __builtin_amdgcn_mfma_f32_16x16x32_bf16(a1[mt][kk], b1[nt][kk], acc[mt + 4][nt + 2], 0, 0, 0);
    __builtin_amdgcn_s_setprio(0);
    if (t < 14) vm_wait8();
    else if (t == 14) vm_drain();
    wave_barrier();
  }
#undef STG_HALF
#undef LDF

  // epilogue — same per-mode layouts as v2 (refcheck-proven).
  const int bb = tm >> 2;
  const int n0 = (tm & 3) << 8;
  const int cb = (tn & 3) << 8;
  if (MODE == 0) {
    const float scl = (tn < 4) ? QSCL : 1.0f;
    unsigned short* dst = (tn < 4) ? qo : ko;
#pragma unroll
    for (int mt = 0; mt < 8; mt++) {
      int tok = n0 + wmb + mt * 16 + l15;
#pragma unroll
      for (int nt = 0; nt < 4; nt++) {
        int c = cb + wnb + nt * 16 + quad * 4;
        int hh = c >> 6, d0 = c & 63;
        uint2 val;
        val.x = f2bf2(acc[mt][nt][0] * scl, acc[mt][nt][1] * scl);
        val.y = f2bf2(acc[mt][nt][2] * scl, acc[mt][nt][3] * scl);
        *(uint2*)&dst[(((size_t)bb * 16 + hh) * 1024 + tok) * 64 + d0] = val;
      }
    }
  } else {
#pragma unroll
    for (int mt = 0; mt < 8; mt++) {
      int tok = n0 + wmb + mt * 16 + quad * 4;
#pragma unroll
      for (int nt = 0; nt < 4; nt++) {
        int c = cb + wnb + nt * 16 + l15;
        int hh = c >> 6, dd = c & 63;
        uint2 val;
        val.x = f2bf2(acc[mt][nt][0], acc[mt][nt][1]);
        val.y = f2bf2(acc[mt][nt][2], acc[mt][nt][3]);
        *(uint2*)&vo[(((size_t)bb * 16 + hh) * 64 + dd) * 1024 + tok] = val;
      }
    }
  }
}

// grid 384 = 32(tm) x 12(tn), flattened; 384%8==0 so the simple bijective
// XCD swizzle applies (each XCD gets 48 consecutive wg = 4 A-panels).
__global__ __launch_bounds__(512, 2) void gemm_qkv(
    const unsigned short* __restrict__ A,
    const unsigned short* __restrict__ Bm,
    unsigned short* __restrict__ qo,
    unsigned short* __restrict__ ko,
    unsigned short* __restrict__ vo) {
  __shared__ unsigned short lds[65536];   // 128 KiB: A dbuf + B dbuf
  const int id = blockIdx.x;
  const int wg = (id & 7) * 48 + (id >> 3);
  const int tm = wg / 12, tn = wg - tm * 12;
  if (tn < 8) qkv_body<0>(lds, A, Bm, qo, ko, vo, tm, tn);
  else        qkv_body<1>(lds, A, Bm, qo, ko, vo, tm, tn);
}

// ---------------- flash attention: S^T, register PV, reflected-bias, MFMA rsum ----
__global__ __launch_bounds__(256, 2) void attn_kernel(
    const unsigned short* __restrict__ Q,
    const unsigned short* __restrict__ Kg,
    const unsigned short* __restrict__ Vt,
    const float* __restrict__ biases,
    unsigned short* __restrict__ Og) {
  __shared__ unsigned short sK[2][64 * 64];
  __shared__ unsigned short sV[2][64 * 64];   // [d][kv], 16B-chunk XOR-swizzled
  __shared__ float sBias2[32 * 63];           // reflected: [di][31 + (qj-kvj)]

  const int bx = blockIdx.x;
  const int bh = bx & 127, qt = bx >> 7;      // qt 0..3; same bh -> same XCD
  const int h = bh & 15, b = bh >> 4;
  const int tid = threadIdx.x, w = tid >> 6, lane = tid & 63;
  const int l15 = lane & 15, quad = lane >> 4;

  const size_t bhs = (size_t)(b * 16 + h);
  const unsigned short* qbase = Q + (bhs * 1024 + (size_t)qt * 256) * 64;
  const unsigned short* kbase = Kg + bhs * 1024 * 64;
  const unsigned short* vbase = Vt + bhs * 64 * 1024;

  for (int t = tid; t < 2048; t += 256) {
    int d = t >> 6, u = t & 63;
    if (u < 63) {
      int dj = u - 31; dj = dj < 0 ? -dj : dj;
      sBias2[d * 63 + u] = biases[h * 1024 + d * 32 + dj] * L2E;
    }
  }

  const int sr0 = w * 16 + (lane >> 3);
  const int sc8 = lane & 7;
  const int sw0 = sc8 ^ (lane >> 3);

  gl_lds16(kbase + (size_t)sr0 * 64 + sw0 * 8,        &sK[0][(w * 16) * 64]);
  gl_lds16(kbase + (size_t)(sr0 + 8) * 64 + sw0 * 8,  &sK[0][(w * 16 + 8) * 64]);
  gl_lds16(vbase + (size_t)sr0 * 1024 + sw0 * 8,      &sV[0][(w * 16) * 64]);
  gl_lds16(vbase + (size_t)(sr0 + 8) * 1024 + sw0 * 8,&sV[0][(w * 16 + 8) * 64]);

  bf16x8 qf[4][2];
#pragma unroll
  for (int qb = 0; qb < 4; qb++)
#pragma unroll
    for (int kd = 0; kd < 2; kd++)
      qf[qb][kd] = *(const bf16x8*)(qbase + (w * 64 + qb * 16 + l15) * 64 + kd * 32 + quad * 8);

  const int qg0 = qt * 256 + w * 64;
  const int qtw = __builtin_amdgcn_readfirstlane(qt * 8 + w * 2);
  int cc2[2][2];
#pragma unroll
  for (int qh = 0; qh < 2; qh++)
#pragma unroll
    for (int kp = 0; kp < 2; kp++)
      cc2[qh][kp] = qh * 16 + l15 - kp * 16 - quad * 4;

  const f32x4 fz = {0.f, 0.f, 0.f, 0.f};
  f32x4 of[4][4], osum[4];
#pragma unroll
  for (int i = 0; i < 4; i++) {
    osum[i] = fz;
#pragma unroll
    for (int j = 0; j < 4; j++) of[i][j] = fz;
  }
  const bf16x4 vones = {(short)0x3F80, (short)0x3F80, (short)0x3F80, (short)0x3F80};

  int buf = 0;
  for (int j0 = 0; j0 < 1024; j0 += 64) {
    vm_drain();
    __syncthreads();
    if (j0 + 64 < 1024) {
      int nb = buf ^ 1, jn = j0 + 64;
      gl_lds16(kbase + (size_t)(jn + sr0) * 64 + sw0 * 8,       &sK[nb][(w * 16) * 64]);
      gl_lds16(kbase + (size_t)(jn + sr0 + 8) * 64 + sw0 * 8,   &sK[nb][(w * 16 + 8) * 64]);
      gl_lds16(vbase + (size_t)sr0 * 1024 + jn + sw0 * 8,       &sV[nb][(w * 16) * 64]);
      gl_lds16(vbase + (size_t)(sr0 + 8) * 1024 + jn + sw0 * 8, &sV[nb][(w * 16 + 8) * 64]);
    }
    const unsigned short* K_ = sK[buf];
    const unsigned short* V_ = sV[buf];
    const int j5 = j0 >> 5;
    const int dh = qtw - j5;                  // qi(qb) = qtw + (qb>>1)
    const float* b0 = sBias2 + abs(dh) * 63 + 31;       // (qb>>1) == (kvb>>1)
    const float* bM = sBias2 + abs(dh - 1) * 63 + 31;   // qb<2, kvb>=2
    const float* bP = sBias2 + abs(dh + 1) * 63 + 31;   // qb>=2, kvb<2

#pragma unroll
    for (int kvb = 0; kvb < 4; kvb++) {
      bf16x8 kf0 = *(const bf16x8*)&K_[(kvb * 16 + l15) * 64 + ((quad ^ (l15 & 7)) << 3)];
      bf16x8 kf1 = *(const bf16x8*)&K_[(kvb * 16 + l15) * 64 + (((4 + quad) ^ (l15 & 7)) << 3)];
      bf16x4 vf[4];
#pragma unroll
      for (int nt = 0; nt < 4; nt++) {
        int d = nt * 16 + l15;
        vf[nt] = *(const bf16x4*)&V_[d * 64 + (((kvb * 2 + (quad >> 1)) ^ (l15 & 7)) << 3) + (quad & 1) * 4];
      }
      const int kp = kvb & 1;
#pragma unroll
      for (int qb = 0; qb < 4; qb++) {
        f32x4 s4 = __builtin_amdgcn_mfma_f32_16x16x32_bf16(kf0, qf[qb][0], fz, 0, 0, 0);
        s4 = __builtin_amdgcn_mfma_f32_16x16x32_bf16(kf1, qf[qb][1], s4, 0, 0, 0);
        const float* bp = (qb < 2) ? ((kvb < 2) ? b0 : bM)
                                   : ((kvb < 2) ? bP : b0);
        const float* bq = bp + cc2[qb & 1][kp];   // bq[-r] = bias for kv=kvjb+r
        float p0 = __builtin_amdgcn_exp2f(s4.x + bq[0]);
        float p1 = __builtin_amdgcn_exp2f(s4.y + bq[-1]);
        float p2 = __builtin_amdgcn_exp2f(s4.z + bq[-2]);
        float p3 = __builtin_amdgcn_exp2f(s4.w + bq[-3]);
        union { unsigned int u[2]; bf16x4 v; } pk;
        pk.u[0] = pk_bf16(p0, p1);
        pk.u[1] = pk_bf16(p2, p3);
#pragma unroll
        for (int nt = 0; nt < 4; nt++)
          of[qb][nt] = __builtin_amdgcn_mfma_f32_16x16x16bf16_1k(pk.v, vf[nt], of[qb][nt], 0, 0, 0);
        osum[qb] = __builtin_amdgcn_mfma_f32_16x16x16bf16_1k(pk.v, vones, osum[qb], 0, 0, 0);
      }
    }
    buf ^= 1;
  }

  const int kvq = quad * 4;
#pragma unroll
  for (int qb = 0; qb < 4; qb++)
#pragma unroll
    for (int r = 0; r < 4; r++) {
      float inv = __builtin_amdgcn_rcpf(osum[qb][r]);   // same C-layout row as of
      int n = qg0 + qb * 16 + kvq + r;
      size_t orow = ((size_t)b * 1024 + n) * 1024 + h * 64;
#pragma unroll
      for (int nt = 0; nt < 4; nt++)
        Og[orow + nt * 16 + l15] = f2bf(of[qb][nt][r] * inv);
    }
}

// ---------------- out-proj GEMM: [8192,1024] x [1024,1024]^T + b ----------------
// R12: 128x64 tiles -> grid 16x64 = 1024 blocks = exactly 4/CU single balanced
// pass (the 128x128 grid was 512 blocks = 2/CU, grid-limited occupancy).
// LDS 36 KB = 3 stages x (8K A + 4K B); 3 gl_lds/tile -> vmcnt(3) partial wait.
__global__ __launch_bounds__(256, 4) void gemm_out_k(
    const unsigned short* __restrict__ A,
    const unsigned short* __restrict__ Bm,
    const float* __restrict__ bias,
    float* __restrict__ out) {
  __shared__ unsigned short sA[3][128 * 32];
  __shared__ unsigned short sB[3][64 * 32];
  const int K = 1024;
  const int tid = threadIdx.x;
  const int w = tid >> 6, lane = tid & 63;
  const int l15 = lane & 15, quad = lane >> 4;
  const int tm = blockIdx.y, tn = blockIdx.x;

  const unsigned short* Ab = A + (size_t)(tm * 128) * K;
  const unsigned short* Bb = Bm + (size_t)(tn * 64) * K;

  const int srowA = w * 32 + (lane >> 2);
  const int srowB = w * 16 + (lane >> 2);
  const int scol = (((lane & 3) ^ ((lane >> 3) & 3))) * 8;   // swizzled content chunk
  const int rsw = (l15 >> 1) & 3;                            // read-side swizzle key

  const f32x4 fz = {0.f, 0.f, 0.f, 0.f};
  f32x4 acc[2][4];
#pragma unroll
  for (int i = 0; i < 2; i++)
#pragma unroll
    for (int j = 0; j < 4; j++) acc[i][j] = fz;

#define OUT_STAGE(kn, nb)                                                          \
  do {                                                                             \
    gl_lds16(Ab + (size_t)srowA * K + (kn) + scol,        &sA[nb][(w * 32) * 32]);      \
    gl_lds16(Ab + (size_t)(srowA + 16) * K + (kn) + scol, &sA[nb][(w * 32 + 16) * 32]); \
    gl_lds16(Bb + (size_t)srowB * K + (kn) + scol,        &sB[nb][(w * 16) * 32]);      \
  } while (0)

  OUT_STAGE(0, 0);
  OUT_STAGE(32, 1);

  int bi = 0;
  for (int k0 = 0; k0 < K; k0 += 32) {
    if (k0 + 64 < K) vm_wait3(); else vm_drain();
    __syncthreads();
    if (k0 + 64 < K) {
      int nb = bi + 2; if (nb >= 3) nb -= 3;
      OUT_STAGE(k0 + 64, nb);
    }
    bf16x8 af[2], bfr[4];
#pragma unroll
    for (int mt = 0; mt < 2; mt++)
      af[mt] = *(const bf16x8*)&sA[bi][(w * 32 + mt * 16 + l15) * 32 + ((quad ^ rsw) << 3)];
#pragma unroll
    for (int nt = 0; nt < 4; nt++)
      bfr[nt] = *(const bf16x8*)&sB[bi][(nt * 16 + l15) * 32 + ((quad ^ rsw) << 3)];
#pragma unroll
    for (int mt = 0; mt < 2; mt++)
#pragma unroll
      for (int nt = 0; nt < 4; nt++)
        acc[mt][nt] = __builtin_amdgcn_mfma_f32_16x16x32_bf16(af[mt], bfr[nt], acc[mt][nt], 0, 0, 0);
    bi = bi + 1; if (bi == 3) bi = 0;
  }
#undef OUT_STAGE

  const int m0 = tm * 128 + w * 32, c0 = tn * 64;
#pragma unroll
  for (int mt = 0; mt < 2; mt++)
#pragma unroll
    for (int nt = 0; nt < 4; nt++)
#pragma unroll
      for (int r = 0; r < 4; r++) {
        int m = m0 + mt * 16 + quad * 4 + r;
        int c = c0 + nt * 16 + l15;
        out[(size_t)m * 1024 + c] = acc[mt][nt][r] + bias[c];
      }
}

extern "C" void kernel_launch(void* const* d_in, const int* in_sizes, int n_in,
                              void* d_out, int out_size, void* d_ws, size_t ws_size,
                              hipStream_t stream) {
  const float* x    = (const float*)d_in[0];
  const float* Wqkv = (const float*)d_in[1];
  const float* ab   = (const float*)d_in[2];
  // d_in[3] (bias_idxs) unused: idx == |n/32-m/32|*32 + |n%32-m%32| analytically
  const float* Wout = (const float*)d_in[4];
  const float* bout = (const float*)d_in[5];
  float* out = (float*)d_out;

  char* ws = (char*)d_ws;
  unsigned short* xb  = (unsigned short*)(ws);                    // 16 MB
  unsigned short* wqb = (unsigned short*)(ws + 16777216);         // 6 MB
  unsigned short* wob = (unsigned short*)(ws + 23068672);         // 2 MB
  unsigned short* qw  = (unsigned short*)(ws + 25165824);         // 16 MB
  unsigned short* kw  = (unsigned short*)(ws + 41943040);         // 16 MB
  unsigned short* vw  = (unsigned short*)(ws + 58720256);         // 16 MB (vT)
  unsigned short* ow  = (unsigned short*)(ws + 75497472);         // 16 MB

  cast3_kernel<<<1536, 256, 0, stream>>>(x, Wqkv, Wout, xb, wqb, wob);
  gemm_qkv<<<384, 512, 0, stream>>>(xb, wqb, qw, kw, vw);
  attn_kernel<<<512, 256, 0, stream>>>(qw, kw, vw, ab, ow);
  gemm_out_k<<<dim3(16, 64), 256, 0, stream>>>(ow, wob, bout, out);
}

// Round 3
// 252.049 us; speedup vs baseline: 1.1500x; 1.0190x over previous
//
#include <hip/hip_runtime.h>

typedef __attribute__((ext_vector_type(8))) short bf16x8;
typedef __attribute__((ext_vector_type(4))) short bf16x4;
typedef __attribute__((ext_vector_type(4))) float f32x4;

#define L2E 1.44269504088896340736f
#define QSCL 0.18033688011112042f   // 0.125 * log2(e)

__device__ inline unsigned short f2bf(float f) {
  union { float f; unsigned int u; } x; x.f = f;
  return (unsigned short)((x.u + 0x8000u) >> 16);
}
__device__ inline unsigned int f2bf2(float a, float b) {
  union { float f; unsigned int u; } xa, xb;
  xa.f = a; xb.f = b;
  return ((xa.u + 0x8000u) >> 16) | (((xb.u + 0x8000u) & 0xFFFF0000u));
}
// HW packed f32->bf16x2 (gfx950 v_cvt_pk_bf16_f32), compile-safe fallback.
__device__ inline unsigned int pk_bf16(float a, float b) {
#if __has_builtin(__builtin_amdgcn_cvt_pk_bf16_f32)
  typedef __attribute__((ext_vector_type(2))) __bf16 bfv2;
  union { bfv2 v; unsigned int u; } x;
  x.v = __builtin_amdgcn_cvt_pk_bf16_f32(a, b);
  return x.u;
#else
  return f2bf2(a, b);
#endif
}

__device__ inline void gl_lds16(const void* g, void* l) {
  __builtin_amdgcn_global_load_lds((const __attribute__((address_space(1))) void*)g,
                                   (__attribute__((address_space(3))) void*)l,
                                   16, 0, 0);
}

__device__ inline void vm_drain() {
  asm volatile("s_waitcnt vmcnt(0)" ::: "memory");
}
__device__ inline void vm_wait3() {   // gemm_out: 3 gl_lds per tile
  asm volatile("s_waitcnt vmcnt(3)" ::: "memory");
}
__device__ inline void vm_wait4() {   // qkv v4: retire A(t+1), keep B(t+2)
  asm volatile("s_waitcnt vmcnt(4)" ::: "memory");
}
__device__ inline void vm_wait8() {   // qkv prologue: tile1 stays in flight
  asm volatile("s_waitcnt vmcnt(8)" ::: "memory");
}

// RAW barrier: no implicit lgkmcnt(0) drain (R1 lesson: __syncthreads'
// pre-barrier drain serializes the schedule). Compiler still emits
// fine-grained lgkmcnt before each MFMA's operand use.
__device__ inline void wave_barrier() {
  asm volatile("" ::: "memory");
  __builtin_amdgcn_s_barrier();
  asm volatile("" ::: "memory");
}

// ---------------- fused cast fp32 -> bf16 (x, W_qkv, W_out) ----------------
#define N4_X  2097152   // 8192*1024/4
#define N4_WQ 786432    // 3072*1024/4
#define N4_WO 262144    // 1024*1024/4
__global__ void cast3_kernel(const float* __restrict__ x,
                             const float* __restrict__ wq,
                             const float* __restrict__ wo,
                             unsigned short* __restrict__ xb,
                             unsigned short* __restrict__ wqb,
                             unsigned short* __restrict__ wob) {
  int i = blockIdx.x * blockDim.x + threadIdx.x;
  int st = gridDim.x * blockDim.x;
  for (; i < N4_X + N4_WQ + N4_WO; i += st) {
    const float* src; unsigned short* dst; int j;
    if (i < N4_X)            { src = x;  dst = xb;  j = i; }
    else if (i < N4_X + N4_WQ){ src = wq; dst = wqb; j = i - N4_X; }
    else                     { src = wo; dst = wob; j = i - N4_X - N4_WQ; }
    float4 v = reinterpret_cast<const float4*>(src)[j];
    ushort4 o;
    o.x = f2bf(v.x); o.y = f2bf(v.y); o.z = f2bf(v.z); o.w = f2bf(v.w);
    reinterpret_cast<ushort4*>(dst)[j] = o;
  }
}

// ---------------- QKV GEMM v4: 256x256xBK64, 8 waves, m-quarter phases ------
// R2 post-mortem: v3's 12/4/8/0 ds_read distribution was m196's "coarse
// phase-split" anti-pattern. v4 re-decomposes phases by m-QUARTERS (phase q
// computes acc[2q..2q+1][all n]); B is register-held for the whole K-tile.
// Fresh ds_reads per phase: 8/4/4/8 (P3 pipelines next tile's a-quarter0 +
// b-lo across the tile boundary). gl_lds: B(t+2)@P1 (B(t) LDS-dead after P0),
// A(t+2)@P3 AFTER the MFMA (a3's lgkm wait precedes issue -> no DMA race).
// One vmcnt(4) per tile at end of P2: retires A(t+1) exactly before P3's
// reads of it; never drains mid-loop (drain once at t==14).
template <int MODE>
__device__ __forceinline__ void qkv_body(
    unsigned short* lds,
    const unsigned short* __restrict__ A,
    const unsigned short* __restrict__ Bm,
    unsigned short* __restrict__ qo,
    unsigned short* __restrict__ ko,
    unsigned short* __restrict__ vo,
    int tm, int tn) {
  const int tid = threadIdx.x;
  const int w = tid >> 6, lane = tid & 63;
  const int l15 = lane & 15, quad = lane >> 4;
  const int wmb = (w >> 2) * 128;     // wave A-row base within 256 tile
  const int wnb = (w & 3) * 64;       // wave B-row base
  const int rl = (w << 3) + (lane >> 3);                    // staging row 0..63
  const int scol = ((lane & 7) ^ ((lane >> 3) & 7)) << 3;   // pre-swizzled chunk
  const int rk = l15 & 7;                                   // read swizzle key

  const unsigned short* Ab = A + (size_t)(tm * 256) * 1024;
  const unsigned short* Bb = Bm + (size_t)(tn * 256) * 1024;

  unsigned short* sA0 = lds;            // 16384 shorts each
  unsigned short* sA1 = lds + 16384;
  unsigned short* sB0 = lds + 32768;
  unsigned short* sB1 = lds + 49152;

#define STG_HALF(Gb, R0, k0, Lb)                                              \
  do {                                                                        \
    gl_lds16((Gb) + (size_t)((R0) + rl) * 1024 + (k0) + scol,                 \
             (Lb) + ((R0) + (w << 3)) * 64);                                  \
    gl_lds16((Gb) + (size_t)((R0) + 64 + rl) * 1024 + (k0) + scol,            \
             (Lb) + ((R0) + 64 + (w << 3)) * 64);                             \
  } while (0)

#define LDF(buf, row, kk) \
  (*(const bf16x8*)&(buf)[(row) * 64 + ((((kk) * 4 + quad) ^ rk) << 3)])

// phase-q MFMA: 2 m-subtiles (2q, 2q+1) x all 4 n x 2 kk = 16 MFMA.
// nt 0,1 use register-held b-lo (bh); nt 2,3 use b-hi (bhi).
#define MFMA_Q(q, aq)                                                          \
  do {                                                                         \
    _Pragma("unroll")                                                          \
    for (int j = 0; j < 2; j++)                                                \
      _Pragma("unroll")                                                        \
      for (int nt = 0; nt < 4; nt++)                                           \
        _Pragma("unroll")                                                      \
        for (int kk = 0; kk < 2; kk++) {                                       \
          bf16x8 bb = (nt < 2) ? bh[nt][kk] : bhi[nt - 2][kk];                 \
          acc[2 * (q) + j][nt] = (MODE == 0)                                   \
            ? __builtin_amdgcn_mfma_f32_16x16x32_bf16(bb, (aq)[j][kk], acc[2 * (q) + j][nt], 0, 0, 0) \
            : __builtin_amdgcn_mfma_f32_16x16x32_bf16((aq)[j][kk], bb, acc[2 * (q) + j][nt], 0, 0, 0); \
        }                                                                      \
  } while (0)

  // prologue: tiles 0 and 1 fully staged (16 gl_lds)
  STG_HALF(Ab, 0, 0, sA0);  STG_HALF(Ab, 128, 0, sA0);
  STG_HALF(Bb, 0, 0, sB0);  STG_HALF(Bb, 128, 0, sB0);
  STG_HALF(Ab, 0, 64, sA1); STG_HALF(Ab, 128, 64, sA1);
  STG_HALF(Bb, 0, 64, sB1); STG_HALF(Bb, 128, 64, sB1);

  const f32x4 fz = {0.f, 0.f, 0.f, 0.f};
  f32x4 acc[8][4];
#pragma unroll
  for (int i = 0; i < 8; i++)
#pragma unroll
    for (int j = 0; j < 4; j++) acc[i][j] = fz;

  vm_wait8();           // tile0 resident (tile1's 8 loads stay in flight)
  wave_barrier();

  // loop-carried: a-quarter0 and b-lo of the CURRENT tile (read pre-loop /
  // at previous tile's P3).
  bf16x8 ah[2][2], bh[2][2];
#pragma unroll
  for (int j = 0; j < 2; j++)
#pragma unroll
    for (int kk = 0; kk < 2; kk++) {
      ah[j][kk] = LDF(sA0, wmb + j * 16 + l15, kk);
      bh[j][kk] = LDF(sB0, wnb + j * 16 + l15, kk);
    }

  for (int t = 0; t < 16; ++t) {
    unsigned short* Ac = (t & 1) ? sA1 : sA0;
    unsigned short* Bc = (t & 1) ? sB1 : sB0;
    unsigned short* An = (t & 1) ? sA0 : sA1;   // tile t+1 buffers
    unsigned short* Bn = (t & 1) ? sB0 : sB1;
    const int kf = (t + 2) << 6;
    bf16x8 a1[2][2], a2[2][2], a3[2][2], bhi[2][2], an[2][2], bn[2][2];

    // ---- P0: read a-quarter1 + b-hi; MFMA q0 (uses ah, bh, bhi)
#pragma unroll
    for (int j = 0; j < 2; j++)
#pragma unroll
      for (int kk = 0; kk < 2; kk++) {
        a1[j][kk]  = LDF(Ac, wmb + (2 + j) * 16 + l15, kk);
        bhi[j][kk] = LDF(Bc, wnb + (2 + j) * 16 + l15, kk);
      }
    wave_barrier();
    __builtin_amdgcn_s_setprio(1);
    MFMA_Q(0, ah);
    __builtin_amdgcn_s_setprio(0);
    wave_barrier();

    // ---- P1: read a-quarter2; stage FULL B(t+2) (B(t) LDS-dead after P0);
    //          MFMA q1
#pragma unroll
    for (int j = 0; j < 2; j++)
#pragma unroll
      for (int kk = 0; kk < 2; kk++)
        a2[j][kk] = LDF(Ac, wmb + (4 + j) * 16 + l15, kk);
    if (t < 14) { STG_HALF(Bb, 0, kf, Bc); STG_HALF(Bb, 128, kf, Bc); }
    wave_barrier();
    __builtin_amdgcn_s_setprio(1);
    MFMA_Q(1, a1);
    __builtin_amdgcn_s_setprio(0);
    wave_barrier();

    // ---- P2: read a-quarter3; MFMA q2; vmcnt(4) retires A(t+1) (needed by
    //          P3's reads), keeps B(t+2)'s 4 loads in flight.
#pragma unroll
    for (int j = 0; j < 2; j++)
#pragma unroll
      for (int kk = 0; kk < 2; kk++)
        a3[j][kk] = LDF(Ac, wmb + (6 + j) * 16 + l15, kk);
    wave_barrier();
    __builtin_amdgcn_s_setprio(1);
    MFMA_Q(2, a2);
    __builtin_amdgcn_s_setprio(0);
    if (t < 14) vm_wait4();
    else if (t == 14) vm_drain();
    wave_barrier();

    // ---- P3: read NEXT tile's a-quarter0 + b-lo (cross-tile pipeline);
    //          MFMA q3; stage FULL A(t+2) AFTER the MFMA (a3's lgkm wait
    //          precedes the gl_lds issue -> no DMA-vs-read race).
    if (t < 15) {
#pragma unroll
      for (int j = 0; j < 2; j++)
#pragma unroll
        for (int kk = 0; kk < 2; kk++) {
          an[j][kk] = LDF(An, wmb + j * 16 + l15, kk);
          bn[j][kk] = LDF(Bn, wnb + j * 16 + l15, kk);
        }
    }
    wave_barrier();
    __builtin_amdgcn_s_setprio(1);
    MFMA_Q(3, a3);
    __builtin_amdgcn_s_setprio(0);
    if (t < 14) { STG_HALF(Ab, 0, kf, Ac); STG_HALF(Ab, 128, kf, Ac); }
    wave_barrier();

    if (t < 15) {
#pragma unroll
      for (int j = 0; j < 2; j++)
#pragma unroll
        for (int kk = 0; kk < 2; kk++) { ah[j][kk] = an[j][kk]; bh[j][kk] = bn[j][kk]; }
    }
  }
#undef STG_HALF
#undef LDF
#undef MFMA_Q

  // epilogue — same per-mode layouts as v2/v3 (refcheck-proven).
  const int bb = tm >> 2;
  const int n0 = (tm & 3) << 8;
  const int cb = (tn & 3) << 8;
  if (MODE == 0) {
    const float scl = (tn < 4) ? QSCL : 1.0f;
    unsigned short* dst = (tn < 4) ? qo : ko;
#pragma unroll
    for (int mt = 0; mt < 8; mt++) {
      int tok = n0 + wmb + mt * 16 + l15;
#pragma unroll
      for (int nt = 0; nt < 4; nt++) {
        int c = cb + wnb + nt * 16 + quad * 4;
        int hh = c >> 6, d0 = c & 63;
        uint2 val;
        val.x = f2bf2(acc[mt][nt][0] * scl, acc[mt][nt][1] * scl);
        val.y = f2bf2(acc[mt][nt][2] * scl, acc[mt][nt][3] * scl);
        *(uint2*)&dst[(((size_t)bb * 16 + hh) * 1024 + tok) * 64 + d0] = val;
      }
    }
  } else {
#pragma unroll
    for (int mt = 0; mt < 8; mt++) {
      int tok = n0 + wmb + mt * 16 + quad * 4;
#pragma unroll
      for (int nt = 0; nt < 4; nt++) {
        int c = cb + wnb + nt * 16 + l15;
        int hh = c >> 6, dd = c & 63;
        uint2 val;
        val.x = f2bf2(acc[mt][nt][0], acc[mt][nt][1]);
        val.y = f2bf2(acc[mt][nt][2], acc[mt][nt][3]);
        *(uint2*)&vo[(((size_t)bb * 16 + hh) * 64 + dd) * 1024 + tok] = val;
      }
    }
  }
}

// grid 384 = 32(tm) x 12(tn), flattened; 384%8==0 so the simple bijective
// XCD swizzle applies (each XCD gets 48 consecutive wg = 4 A-panels).
__global__ __launch_bounds__(512, 2) void gemm_qkv(
    const unsigned short* __restrict__ A,
    const unsigned short* __restrict__ Bm,
    unsigned short* __restrict__ qo,
    unsigned short* __restrict__ ko,
    unsigned short* __restrict__ vo) {
  __shared__ unsigned short lds[65536];   // 128 KiB: A dbuf + B dbuf
  const int id = blockIdx.x;
  const int wg = (id & 7) * 48 + (id >> 3);
  const int tm = wg / 12, tn = wg - tm * 12;
  if (tn < 8) qkv_body<0>(lds, A, Bm, qo, ko, vo, tm, tn);
  else        qkv_body<1>(lds, A, Bm, qo, ko, vo, tm, tn);
}

// ---------------- flash attention: S^T, register PV, reflected-bias, MFMA rsum ----
__global__ __launch_bounds__(256, 2) void attn_kernel(
    const unsigned short* __restrict__ Q,
    const unsigned short* __restrict__ Kg,
    const unsigned short* __restrict__ Vt,
    const float* __restrict__ biases,
    unsigned short* __restrict__ Og) {
  __shared__ unsigned short sK[2][64 * 64];
  __shared__ unsigned short sV[2][64 * 64];   // [d][kv], 16B-chunk XOR-swizzled
  __shared__ float sBias2[32 * 63];           // reflected: [di][31 + (qj-kvj)]

  const int bx = blockIdx.x;
  const int bh = bx & 127, qt = bx >> 7;      // qt 0..3; same bh -> same XCD
  const int h = bh & 15, b = bh >> 4;
  const int tid = threadIdx.x, w = tid >> 6, lane = tid & 63;
  const int l15 = lane & 15, quad = lane >> 4;

  const size_t bhs = (size_t)(b * 16 + h);
  const unsigned short* qbase = Q + (bhs * 1024 + (size_t)qt * 256) * 64;
  const unsigned short* kbase = Kg + bhs * 1024 * 64;
  const unsigned short* vbase = Vt + bhs * 64 * 1024;

  for (int t = tid; t < 2048; t += 256) {
    int d = t >> 6, u = t & 63;
    if (u < 63) {
      int dj = u - 31; dj = dj < 0 ? -dj : dj;
      sBias2[d * 63 + u] = biases[h * 1024 + d * 32 + dj] * L2E;
    }
  }

  const int sr0 = w * 16 + (lane >> 3);
  const int sc8 = lane & 7;
  const int sw0 = sc8 ^ (lane >> 3);

  gl_lds16(kbase + (size_t)sr0 * 64 + sw0 * 8,        &sK[0][(w * 16) * 64]);
  gl_lds16(kbase + (size_t)(sr0 + 8) * 64 + sw0 * 8,  &sK[0][(w * 16 + 8) * 64]);
  gl_lds16(vbase + (size_t)sr0 * 1024 + sw0 * 8,      &sV[0][(w * 16) * 64]);
  gl_lds16(vbase + (size_t)(sr0 + 8) * 1024 + sw0 * 8,&sV[0][(w * 16 + 8) * 64]);

  bf16x8 qf[4][2];
#pragma unroll
  for (int qb = 0; qb < 4; qb++)
#pragma unroll
    for (int kd = 0; kd < 2; kd++)
      qf[qb][kd] = *(const bf16x8*)(qbase + (w * 64 + qb * 16 + l15) * 64 + kd * 32 + quad * 8);

  const int qg0 = qt * 256 + w * 64;
  const int qtw = __builtin_amdgcn_readfirstlane(qt * 8 + w * 2);
  int cc2[2][2];
#pragma unroll
  for (int qh = 0; qh < 2; qh++)
#pragma unroll
    for (int kp = 0; kp < 2; kp++)
      cc2[qh][kp] = qh * 16 + l15 - kp * 16 - quad * 4;

  const f32x4 fz = {0.f, 0.f, 0.f, 0.f};
  f32x4 of[4][4], osum[4];
#pragma unroll
  for (int i = 0; i < 4; i++) {
    osum[i] = fz;
#pragma unroll
    for (int j = 0; j < 4; j++) of[i][j] = fz;
  }
  const bf16x4 vones = {(short)0x3F80, (short)0x3F80, (short)0x3F80, (short)0x3F80};

  int buf = 0;
  for (int j0 = 0; j0 < 1024; j0 += 64) {
    vm_drain();
    __syncthreads();
    if (j0 + 64 < 1024) {
      int nb = buf ^ 1, jn = j0 + 64;
      gl_lds16(kbase + (size_t)(jn + sr0) * 64 + sw0 * 8,       &sK[nb][(w * 16) * 64]);
      gl_lds16(kbase + (size_t)(jn + sr0 + 8) * 64 + sw0 * 8,   &sK[nb][(w * 16 + 8) * 64]);
      gl_lds16(vbase + (size_t)sr0 * 1024 + jn + sw0 * 8,       &sV[nb][(w * 16) * 64]);
      gl_lds16(vbase + (size_t)(sr0 + 8) * 1024 + jn + sw0 * 8, &sV[nb][(w * 16 + 8) * 64]);
    }
    const unsigned short* K_ = sK[buf];
    const unsigned short* V_ = sV[buf];
    const int j5 = j0 >> 5;
    const int dh = qtw - j5;                  // qi(qb) = qtw + (qb>>1)
    const float* b0 = sBias2 + abs(dh) * 63 + 31;       // (qb>>1) == (kvb>>1)
    const float* bM = sBias2 + abs(dh - 1) * 63 + 31;   // qb<2, kvb>=2
    const float* bP = sBias2 + abs(dh + 1) * 63 + 31;   // qb>=2, kvb<2

#pragma unroll
    for (int kvb = 0; kvb < 4; kvb++) {
      bf16x8 kf0 = *(const bf16x8*)&K_[(kvb * 16 + l15) * 64 + ((quad ^ (l15 & 7)) << 3)];
      bf16x8 kf1 = *(const bf16x8*)&K_[(kvb * 16 + l15) * 64 + (((4 + quad) ^ (l15 & 7)) << 3)];
      bf16x4 vf[4];
#pragma unroll
      for (int nt = 0; nt < 4; nt++) {
        int d = nt * 16 + l15;
        vf[nt] = *(const bf16x4*)&V_[d * 64 + (((kvb * 2 + (quad >> 1)) ^ (l15 & 7)) << 3) + (quad & 1) * 4];
      }
      const int kp = kvb & 1;
#pragma unroll
      for (int qb = 0; qb < 4; qb++) {
        f32x4 s4 = __builtin_amdgcn_mfma_f32_16x16x32_bf16(kf0, qf[qb][0], fz, 0, 0, 0);
        s4 = __builtin_amdgcn_mfma_f32_16x16x32_bf16(kf1, qf[qb][1], s4, 0, 0, 0);
        const float* bp = (qb < 2) ? ((kvb < 2) ? b0 : bM)
                                   : ((kvb < 2) ? bP : b0);
        const float* bq = bp + cc2[qb & 1][kp];   // bq[-r] = bias for kv=kvjb+r
        float p0 = __builtin_amdgcn_exp2f(s4.x + bq[0]);
        float p1 = __builtin_amdgcn_exp2f(s4.y + bq[-1]);
        float p2 = __builtin_amdgcn_exp2f(s4.z + bq[-2]);
        float p3 = __builtin_amdgcn_exp2f(s4.w + bq[-3]);
        union { unsigned int u[2]; bf16x4 v; } pk;
        pk.u[0] = pk_bf16(p0, p1);
        pk.u[1] = pk_bf16(p2, p3);
#pragma unroll
        for (int nt = 0; nt < 4; nt++)
          of[qb][nt] = __builtin_amdgcn_mfma_f32_16x16x16bf16_1k(pk.v, vf[nt], of[qb][nt], 0, 0, 0);
        osum[qb] = __builtin_amdgcn_mfma_f32_16x16x16bf16_1k(pk.v, vones, osum[qb], 0, 0, 0);
      }
    }
    buf ^= 1;
  }

  const int kvq = quad * 4;
#pragma unroll
  for (int qb = 0; qb < 4; qb++)
#pragma unroll
    for (int r = 0; r < 4; r++) {
      float inv = __builtin_amdgcn_rcpf(osum[qb][r]);   // same C-layout row as of
      int n = qg0 + qb * 16 + kvq + r;
      size_t orow = ((size_t)b * 1024 + n) * 1024 + h * 64;
#pragma unroll
      for (int nt = 0; nt < 4; nt++)
        Og[orow + nt * 16 + l15] = f2bf(of[qb][nt][r] * inv);
    }
}

// ---------------- out-proj GEMM: [8192,1024] x [1024,1024]^T + b ----------------
// R12: 128x64 tiles -> grid 16x64 = 1024 blocks = exactly 4/CU single balanced
// pass (the 128x128 grid was 512 blocks = 2/CU, grid-limited occupancy).
// LDS 36 KB = 3 stages x (8K A + 4K B); 3 gl_lds/tile -> vmcnt(3) partial wait.
__global__ __launch_bounds__(256, 4) void gemm_out_k(
    const unsigned short* __restrict__ A,
    const unsigned short* __restrict__ Bm,
    const float* __restrict__ bias,
    float* __restrict__ out) {
  __shared__ unsigned short sA[3][128 * 32];
  __shared__ unsigned short sB[3][64 * 32];
  const int K = 1024;
  const int tid = threadIdx.x;
  const int w = tid >> 6, lane = tid & 63;
  const int l15 = lane & 15, quad = lane >> 4;
  const int tm = blockIdx.y, tn = blockIdx.x;

  const unsigned short* Ab = A + (size_t)(tm * 128) * K;
  const unsigned short* Bb = Bm + (size_t)(tn * 64) * K;

  const int srowA = w * 32 + (lane >> 2);
  const int srowB = w * 16 + (lane >> 2);
  const int scol = (((lane & 3) ^ ((lane >> 3) & 3))) * 8;   // swizzled content chunk
  const int rsw = (l15 >> 1) & 3;                            // read-side swizzle key

  const f32x4 fz = {0.f, 0.f, 0.f, 0.f};
  f32x4 acc[2][4];
#pragma unroll
  for (int i = 0; i < 2; i++)
#pragma unroll
    for (int j = 0; j < 4; j++) acc[i][j] = fz;

#define OUT_STAGE(kn, nb)                                                          \
  do {                                                                             \
    gl_lds16(Ab + (size_t)srowA * K + (kn) + scol,        &sA[nb][(w * 32) * 32]);      \
    gl_lds16(Ab + (size_t)(srowA + 16) * K + (kn) + scol, &sA[nb][(w * 32 + 16) * 32]); \
    gl_lds16(Bb + (size_t)srowB * K + (kn) + scol,        &sB[nb][(w * 16) * 32]);      \
  } while (0)

  OUT_STAGE(0, 0);
  OUT_STAGE(32, 1);

  int bi = 0;
  for (int k0 = 0; k0 < K; k0 += 32) {
    if (k0 + 64 < K) vm_wait3(); else vm_drain();
    __syncthreads();
    if (k0 + 64 < K) {
      int nb = bi + 2; if (nb >= 3) nb -= 3;
      OUT_STAGE(k0 + 64, nb);
    }
    bf16x8 af[2], bfr[4];
#pragma unroll
    for (int mt = 0; mt < 2; mt++)
      af[mt] = *(const bf16x8*)&sA[bi][(w * 32 + mt * 16 + l15) * 32 + ((quad ^ rsw) << 3)];
#pragma unroll
    for (int nt = 0; nt < 4; nt++)
      bfr[nt] = *(const bf16x8*)&sB[bi][(nt * 16 + l15) * 32 + ((quad ^ rsw) << 3)];
#pragma unroll
    for (int mt = 0; mt < 2; mt++)
#pragma unroll
      for (int nt = 0; nt < 4; nt++)
        acc[mt][nt] = __builtin_amdgcn_mfma_f32_16x16x32_bf16(af[mt], bfr[nt], acc[mt][nt], 0, 0, 0);
    bi = bi + 1; if (bi == 3) bi = 0;
  }
#undef OUT_STAGE

  const int m0 = tm * 128 + w * 32, c0 = tn * 64;
#pragma unroll
  for (int mt = 0; mt < 2; mt++)
#pragma unroll
    for (int nt = 0; nt < 4; nt++)
#pragma unroll
      for (int r = 0; r < 4; r++) {
        int m = m0 + mt * 16 + quad * 4 + r;
        int c = c0 + nt * 16 + l15;
        out[(size_t)m * 1024 + c] = acc[mt][nt][r] + bias[c];
      }
}

extern "C" void kernel_launch(void* const* d_in, const int* in_sizes, int n_in,
                              void* d_out, int out_size, void* d_ws, size_t ws_size,
                              hipStream_t stream) {
  const float* x    = (const float*)d_in[0];
  const float* Wqkv = (const float*)d_in[1];
  const float* ab   = (const float*)d_in[2];
  // d_in[3] (bias_idxs) unused: idx == |n/32-m/32|*32 + |n%32-m%32| analytically
  const float* Wout = (const float*)d_in[4];
  const float* bout = (const float*)d_in[5];
  float* out = (float*)d_out;

  char* ws = (char*)d_ws;
  unsigned short* xb  = (unsigned short*)(ws);                    // 16 MB
  unsigned short* wqb = (unsigned short*)(ws + 16777216);         // 6 MB
  unsigned short* wob = (unsigned short*)(ws + 23068672);         // 2 MB
  unsigned short* qw  = (unsigned short*)(ws + 25165824);         // 16 MB
  unsigned short* kw  = (unsigned short*)(ws + 41943040);         // 16 MB
  unsigned short* vw  = (unsigned short*)(ws + 58720256);         // 16 MB (vT)
  unsigned short* ow  = (unsigned short*)(ws + 75497472);         // 16 MB

  cast3_kernel<<<1536, 256, 0, stream>>>(x, Wqkv, Wout, xb, wqb, wob);
  gemm_qkv<<<384, 512, 0, stream>>>(xb, wqb, qw, kw, vw);
  attn_kernel<<<512, 256, 0, stream>>>(qw, kw, vw, ab, ow);
  gemm_out_k<<<dim3(16, 64), 256, 0, stream>>>(ow, wob, bout, out);
}

// Round 4
// 249.149 us; speedup vs baseline: 1.1634x; 1.0116x over previous
//
#include <hip/hip_runtime.h>

typedef __attribute__((ext_vector_type(8))) short bf16x8;
typedef __attribute__((ext_vector_type(4))) short bf16x4;
typedef __attribute__((ext_vector_type(4))) float f32x4;

#define L2E 1.44269504088896340736f
#define QSCL 0.18033688011112042f   // 0.125 * log2(e)

__device__ inline unsigned short f2bf(float f) {
  union { float f; unsigned int u; } x; x.f = f;
  return (unsigned short)((x.u + 0x8000u) >> 16);
}
__device__ inline unsigned int f2bf2(float a, float b) {
  union { float f; unsigned int u; } xa, xb;
  xa.f = a; xb.f = b;
  return ((xa.u + 0x8000u) >> 16) | (((xb.u + 0x8000u) & 0xFFFF0000u));
}
// HW packed f32->bf16x2 (gfx950 v_cvt_pk_bf16_f32), compile-safe fallback.
__device__ inline unsigned int pk_bf16(float a, float b) {
#if __has_builtin(__builtin_amdgcn_cvt_pk_bf16_f32)
  typedef __attribute__((ext_vector_type(2))) __bf16 bfv2;
  union { bfv2 v; unsigned int u; } x;
  x.v = __builtin_amdgcn_cvt_pk_bf16_f32(a, b);
  return x.u;
#else
  return f2bf2(a, b);
#endif
}

__device__ inline void gl_lds16(const void* g, void* l) {
  __builtin_amdgcn_global_load_lds((const __attribute__((address_space(1))) void*)g,
                                   (__attribute__((address_space(3))) void*)l,
                                   16, 0, 0);
}

// Full drain (attn): compiler emits NO vmcnt before s_barrier here (R4 race
// proved it) — so the wait is entirely ours to specify.
__device__ inline void vm_drain() {
  asm volatile("s_waitcnt vmcnt(0)" ::: "memory");
}
// Partial drains for the 3-stage GEMM pipelines (placed BEFORE staging i+2):
// outstanding = tiles i, i+1; draining to (loads/tile) retires exactly tile i
// while tile i+1 stays in flight across the barrier.
__device__ inline void vm_wait4() {   // gemm_qkv: 4 gl_lds per tile
  asm volatile("s_waitcnt vmcnt(4)" ::: "memory");
}
__device__ inline void vm_wait3() {   // gemm_out: 3 gl_lds per tile
  asm volatile("s_waitcnt vmcnt(3)" ::: "memory");
}

// ---------------- fused cast fp32 -> bf16 (x, W_qkv, W_out) ----------------
#define N4_X  2097152   // 8192*1024/4
#define N4_WQ 786432    // 3072*1024/4
#define N4_WO 262144    // 1024*1024/4
__global__ void cast3_kernel(const float* __restrict__ x,
                             const float* __restrict__ wq,
                             const float* __restrict__ wo,
                             unsigned short* __restrict__ xb,
                             unsigned short* __restrict__ wqb,
                             unsigned short* __restrict__ wob) {
  int i = blockIdx.x * blockDim.x + threadIdx.x;
  int st = gridDim.x * blockDim.x;
  for (; i < N4_X + N4_WQ + N4_WO; i += st) {
    const float* src; unsigned short* dst; int j;
    if (i < N4_X)            { src = x;  dst = xb;  j = i; }
    else if (i < N4_X + N4_WQ){ src = wq; dst = wqb; j = i - N4_X; }
    else                     { src = wo; dst = wob; j = i - N4_X - N4_WQ; }
    float4 v = reinterpret_cast<const float4*>(src)[j];
    ushort4 o;
    o.x = f2bf(v.x); o.y = f2bf(v.y); o.z = f2bf(v.z); o.w = f2bf(v.w);
    reinterpret_cast<ushort4*>(dst)[j] = o;
  }
}

// ---------------- QKV GEMM: [8192,1024] x [3072,1024]^T ----------------
// v1 3-stage structure (proven 76.6 us; R1-R3 8-phase ports all landed
// 77.7-112 us -> abandoned). 3-stage LDS pipeline (48 KB -> 3 blocks/CU;
// 1536 blocks = 2 balanced passes), prefetch distance 2, vmcnt(4) partial
// wait. R3 adds only an XCD-chunked block swizzle (launch side): the 24
// blocks sharing one A-panel now land on one XCD's L2 instead of 8.
template <int MODE>
__device__ __forceinline__ void gemm_qkv_body(
    unsigned short* __restrict__ sA,   // [3][128*32] flattened
    unsigned short* __restrict__ sB,
    const unsigned short* __restrict__ A,
    const unsigned short* __restrict__ Bm,
    unsigned short* __restrict__ qo,
    unsigned short* __restrict__ ko,
    unsigned short* __restrict__ vo,
    int tm, int tn) {
  const int K = 1024;
  const int tid = threadIdx.x;
  const int w = tid >> 6, lane = tid & 63;
  const int l15 = lane & 15, quad = lane >> 4;
  const int wm = (w >> 1) * 64, wn = (w & 1) * 64;

  const unsigned short* Ab = A + (size_t)(tm * 128) * K;
  const unsigned short* Bb = Bm + (size_t)(tn * 128) * K;

  const int srow = w * 32 + (lane >> 2);
  const int scol = (((lane & 3) ^ ((lane >> 3) & 3))) * 8;   // swizzled content chunk
  const int rsw = (l15 >> 1) & 3;                            // read-side swizzle key

  const f32x4 fz = {0.f, 0.f, 0.f, 0.f};
  f32x4 acc[4][4];
#pragma unroll
  for (int i = 0; i < 4; i++)
#pragma unroll
    for (int j = 0; j < 4; j++) acc[i][j] = fz;

#define QKV_STAGE(kn, nb)                                                        \
  do {                                                                           \
    gl_lds16(Ab + (size_t)srow * K + (kn) + scol,        &sA[(nb) * 4096 + (w * 32) * 32]);      \
    gl_lds16(Ab + (size_t)(srow + 16) * K + (kn) + scol, &sA[(nb) * 4096 + (w * 32 + 16) * 32]); \
    gl_lds16(Bb + (size_t)srow * K + (kn) + scol,        &sB[(nb) * 4096 + (w * 32) * 32]);      \
    gl_lds16(Bb + (size_t)(srow + 16) * K + (kn) + scol, &sB[(nb) * 4096 + (w * 32 + 16) * 32]); \
  } while (0)

  QKV_STAGE(0, 0);
  QKV_STAGE(32, 1);

  int bi = 0;
  for (int k0 = 0; k0 < K; k0 += 32) {
    if (k0 + 64 < K) vm_wait4(); else vm_drain();
    __syncthreads();
    if (k0 + 64 < K) {
      int nb = bi + 2; if (nb >= 3) nb -= 3;
      QKV_STAGE(k0 + 64, nb);
    }
    bf16x8 af[4], bfr[4];
#pragma unroll
    for (int mt = 0; mt < 4; mt++)
      af[mt] = *(const bf16x8*)&sA[bi * 4096 + (wm + mt * 16 + l15) * 32 + ((quad ^ rsw) << 3)];
#pragma unroll
    for (int nt = 0; nt < 4; nt++)
      bfr[nt] = *(const bf16x8*)&sB[bi * 4096 + (wn + nt * 16 + l15) * 32 + ((quad ^ rsw) << 3)];
#pragma unroll
    for (int mt = 0; mt < 4; mt++)
#pragma unroll
      for (int nt = 0; nt < 4; nt++) {
        if (MODE == 0)
          acc[mt][nt] = __builtin_amdgcn_mfma_f32_16x16x32_bf16(bfr[nt], af[mt], acc[mt][nt], 0, 0, 0);
        else
          acc[mt][nt] = __builtin_amdgcn_mfma_f32_16x16x32_bf16(af[mt], bfr[nt], acc[mt][nt], 0, 0, 0);
      }
    bi = bi + 1; if (bi == 3) bi = 0;
  }
#undef QKV_STAGE

  const int m0 = tm * 128;
  const int bb = m0 >> 10, n0 = m0 & 1023;
  const int cbase = (tn * 128) & 1023;

  if (MODE == 0) {
    const int which = tn >> 3;                 // 0:q 1:k
    const float scl = (which == 0) ? QSCL : 1.0f;
    unsigned short* dst = (which == 0) ? qo : ko;
#pragma unroll
    for (int mt = 0; mt < 4; mt++) {
      int tok = n0 + wm + mt * 16 + l15;
#pragma unroll
      for (int nt = 0; nt < 4; nt++) {
        int c = cbase + wn + nt * 16 + quad * 4;
        int hh = c >> 6, d0 = c & 63;
        uint2 val;
        val.x = f2bf2(acc[mt][nt][0] * scl, acc[mt][nt][1] * scl);
        val.y = f2bf2(acc[mt][nt][2] * scl, acc[mt][nt][3] * scl);
        *(uint2*)&dst[(((size_t)bb * 16 + hh) * 1024 + tok) * 64 + d0] = val;
      }
    }
  } else {
#pragma unroll
    for (int mt = 0; mt < 4; mt++) {
      int tok = n0 + wm + mt * 16 + quad * 4;
#pragma unroll
      for (int nt = 0; nt < 4; nt++) {
        int c = cbase + wn + nt * 16 + l15;
        int hh = c >> 6, dd = c & 63;
        uint2 val;
        val.x = f2bf2(acc[mt][nt][0], acc[mt][nt][1]);
        val.y = f2bf2(acc[mt][nt][2], acc[mt][nt][3]);
        *(uint2*)&vo[(((size_t)bb * 16 + hh) * 64 + dd) * 1024 + tok] = val;
      }
    }
  }
}

// 1D grid 1536; XCD-chunked bijective swizzle: xcd = bid&7 owns 192
// consecutive (tm-major) tiles = 8 full A-panels -> each A-panel is fetched
// into exactly one XCD's L2 (was: scattered across all 8).
__global__ __launch_bounds__(256, 3) void gemm_qkv(
    const unsigned short* __restrict__ A,
    const unsigned short* __restrict__ Bm,
    unsigned short* __restrict__ qo,
    unsigned short* __restrict__ ko,
    unsigned short* __restrict__ vo) {
  __shared__ unsigned short sA[3][128 * 32];
  __shared__ unsigned short sB[3][128 * 32];
  const int bid = blockIdx.x;
  const int wg = (bid & 7) * 192 + (bid >> 3);   // 1536/8 = 192 per XCD
  const int tm = wg / 24, tn = wg - tm * 24;     // tm-major enumeration
  if (tn < 16) gemm_qkv_body<0>(&sA[0][0], &sB[0][0], A, Bm, qo, ko, vo, tm, tn);
  else         gemm_qkv_body<1>(&sA[0][0], &sB[0][0], A, Bm, qo, ko, vo, tm, tn);
}

// ---------------- flash attention: S^T, register PV, reflected-bias, MFMA rsum ----
__global__ __launch_bounds__(256, 2) void attn_kernel(
    const unsigned short* __restrict__ Q,
    const unsigned short* __restrict__ Kg,
    const unsigned short* __restrict__ Vt,
    const float* __restrict__ biases,
    unsigned short* __restrict__ Og) {
  __shared__ unsigned short sK[2][64 * 64];
  __shared__ unsigned short sV[2][64 * 64];   // [d][kv], 16B-chunk XOR-swizzled
  __shared__ float sBias2[32 * 63];           // reflected: [di][31 + (qj-kvj)]

  const int bx = blockIdx.x;
  const int bh = bx & 127, qt = bx >> 7;      // qt 0..3; same bh -> same XCD
  const int h = bh & 15, b = bh >> 4;
  const int tid = threadIdx.x, w = tid >> 6, lane = tid & 63;
  const int l15 = lane & 15, quad = lane >> 4;

  const size_t bhs = (size_t)(b * 16 + h);
  const unsigned short* qbase = Q + (bhs * 1024 + (size_t)qt * 256) * 64;
  const unsigned short* kbase = Kg + bhs * 1024 * 64;
  const unsigned short* vbase = Vt + bhs * 64 * 1024;

  for (int t = tid; t < 2048; t += 256) {
    int d = t >> 6, u = t & 63;
    if (u < 63) {
      int dj = u - 31; dj = dj < 0 ? -dj : dj;
      sBias2[d * 63 + u] = biases[h * 1024 + d * 32 + dj] * L2E;
    }
  }

  const int sr0 = w * 16 + (lane >> 3);
  const int sc8 = lane & 7;
  const int sw0 = sc8 ^ (lane >> 3);

  gl_lds16(kbase + (size_t)sr0 * 64 + sw0 * 8,        &sK[0][(w * 16) * 64]);
  gl_lds16(kbase + (size_t)(sr0 + 8) * 64 + sw0 * 8,  &sK[0][(w * 16 + 8) * 64]);
  gl_lds16(vbase + (size_t)sr0 * 1024 + sw0 * 8,      &sV[0][(w * 16) * 64]);
  gl_lds16(vbase + (size_t)(sr0 + 8) * 1024 + sw0 * 8,&sV[0][(w * 16 + 8) * 64]);

  bf16x8 qf[4][2];
#pragma unroll
  for (int qb = 0; qb < 4; qb++)
#pragma unroll
    for (int kd = 0; kd < 2; kd++)
      qf[qb][kd] = *(const bf16x8*)(qbase + (w * 64 + qb * 16 + l15) * 64 + kd * 32 + quad * 8);

  const int qg0 = qt * 256 + w * 64;
  const int qtw = __builtin_amdgcn_readfirstlane(qt * 8 + w * 2);
  int cc2[2][2];
#pragma unroll
  for (int qh = 0; qh < 2; qh++)
#pragma unroll
    for (int kp = 0; kp < 2; kp++)
      cc2[qh][kp] = qh * 16 + l15 - kp * 16 - quad * 4;

  const f32x4 fz = {0.f, 0.f, 0.f, 0.f};
  f32x4 of[4][4], osum[4];
#pragma unroll
  for (int i = 0; i < 4; i++) {
    osum[i] = fz;
#pragma unroll
    for (int j = 0; j < 4; j++) of[i][j] = fz;
  }
  const bf16x4 vones = {(short)0x3F80, (short)0x3F80, (short)0x3F80, (short)0x3F80};

  int buf = 0;
  for (int j0 = 0; j0 < 1024; j0 += 64) {
    vm_drain();
    __syncthreads();
    if (j0 + 64 < 1024) {
      int nb = buf ^ 1, jn = j0 + 64;
      gl_lds16(kbase + (size_t)(jn + sr0) * 64 + sw0 * 8,       &sK[nb][(w * 16) * 64]);
      gl_lds16(kbase + (size_t)(jn + sr0 + 8) * 64 + sw0 * 8,   &sK[nb][(w * 16 + 8) * 64]);
      gl_lds16(vbase + (size_t)sr0 * 1024 + jn + sw0 * 8,       &sV[nb][(w * 16) * 64]);
      gl_lds16(vbase + (size_t)(sr0 + 8) * 1024 + jn + sw0 * 8, &sV[nb][(w * 16 + 8) * 64]);
    }
    const unsigned short* K_ = sK[buf];
    const unsigned short* V_ = sV[buf];
    const int j5 = j0 >> 5;
    const int dh = qtw - j5;                  // qi(qb) = qtw + (qb>>1)
    const float* b0 = sBias2 + abs(dh) * 63 + 31;       // (qb>>1) == (kvb>>1)
    const float* bM = sBias2 + abs(dh - 1) * 63 + 31;   // qb<2, kvb>=2
    const float* bP = sBias2 + abs(dh + 1) * 63 + 31;   // qb>=2, kvb<2

#pragma unroll
    for (int kvb = 0; kvb < 4; kvb++) {
      bf16x8 kf0 = *(const bf16x8*)&K_[(kvb * 16 + l15) * 64 + ((quad ^ (l15 & 7)) << 3)];
      bf16x8 kf1 = *(const bf16x8*)&K_[(kvb * 16 + l15) * 64 + (((4 + quad) ^ (l15 & 7)) << 3)];
      bf16x4 vf[4];
#pragma unroll
      for (int nt = 0; nt < 4; nt++) {
        int d = nt * 16 + l15;
        vf[nt] = *(const bf16x4*)&V_[d * 64 + (((kvb * 2 + (quad >> 1)) ^ (l15 & 7)) << 3) + (quad & 1) * 4];
      }
      const int kp = kvb & 1;
#pragma unroll
      for (int qb = 0; qb < 4; qb++) {
        f32x4 s4 = __builtin_amdgcn_mfma_f32_16x16x32_bf16(kf0, qf[qb][0], fz, 0, 0, 0);
        s4 = __builtin_amdgcn_mfma_f32_16x16x32_bf16(kf1, qf[qb][1], s4, 0, 0, 0);
        const float* bp = (qb < 2) ? ((kvb < 2) ? b0 : bM)
                                   : ((kvb < 2) ? bP : b0);
        const float* bq = bp + cc2[qb & 1][kp];   // bq[-r] = bias for kv=kvjb+r
        float p0 = __builtin_amdgcn_exp2f(s4.x + bq[0]);
        float p1 = __builtin_amdgcn_exp2f(s4.y + bq[-1]);
        float p2 = __builtin_amdgcn_exp2f(s4.z + bq[-2]);
        float p3 = __builtin_amdgcn_exp2f(s4.w + bq[-3]);
        union { unsigned int u[2]; bf16x4 v; } pk;
        pk.u[0] = pk_bf16(p0, p1);
        pk.u[1] = pk_bf16(p2, p3);
#pragma unroll
        for (int nt = 0; nt < 4; nt++)
          of[qb][nt] = __builtin_amdgcn_mfma_f32_16x16x16bf16_1k(pk.v, vf[nt], of[qb][nt], 0, 0, 0);
        osum[qb] = __builtin_amdgcn_mfma_f32_16x16x16bf16_1k(pk.v, vones, osum[qb], 0, 0, 0);
      }
    }
    buf ^= 1;
  }

  const int kvq = quad * 4;
#pragma unroll
  for (int qb = 0; qb < 4; qb++)
#pragma unroll
    for (int r = 0; r < 4; r++) {
      float inv = __builtin_amdgcn_rcpf(osum[qb][r]);   // same C-layout row as of
      int n = qg0 + qb * 16 + kvq + r;
      size_t orow = ((size_t)b * 1024 + n) * 1024 + h * 64;
#pragma unroll
      for (int nt = 0; nt < 4; nt++)
        Og[orow + nt * 16 + l15] = f2bf(of[qb][nt][r] * inv);
    }
}

// ---------------- out-proj GEMM: [8192,1024] x [1024,1024]^T + b ----------------
// R12: 128x64 tiles -> 1024 blocks = exactly 4/CU single balanced pass.
// LDS 36 KB = 3 stages x (8K A + 4K B); 3 gl_lds/tile -> vmcnt(3) partial wait.
// R3: XCD-chunked swizzle (tm-major): the 16 blocks sharing a 256 KB A-panel
// now sit on one XCD (was: all 8) -> A fetched once, not 8x.
__global__ __launch_bounds__(256, 4) void gemm_out_k(
    const unsigned short* __restrict__ A,
    const unsigned short* __restrict__ Bm,
    const float* __restrict__ bias,
    float* __restrict__ out) {
  __shared__ unsigned short sA[3][128 * 32];
  __shared__ unsigned short sB[3][64 * 32];
  const int K = 1024;
  const int tid = threadIdx.x;
  const int w = tid >> 6, lane = tid & 63;
  const int l15 = lane & 15, quad = lane >> 4;
  const int bid = blockIdx.x;
  const int wg = (bid & 7) * 128 + (bid >> 3);   // 1024/8 = 128 per XCD
  const int tm = wg >> 4, tn = wg & 15;          // tm-major enumeration

  const unsigned short* Ab = A + (size_t)(tm * 128) * K;
  const unsigned short* Bb = Bm + (size_t)(tn * 64) * K;

  const int srowA = w * 32 + (lane >> 2);
  const int srowB = w * 16 + (lane >> 2);
  const int scol = (((lane & 3) ^ ((lane >> 3) & 3))) * 8;   // swizzled content chunk
  const int rsw = (l15 >> 1) & 3;                            // read-side swizzle key

  const f32x4 fz = {0.f, 0.f, 0.f, 0.f};
  f32x4 acc[2][4];
#pragma unroll
  for (int i = 0; i < 2; i++)
#pragma unroll
    for (int j = 0; j < 4; j++) acc[i][j] = fz;

#define OUT_STAGE(kn, nb)                                                          \
  do {                                                                             \
    gl_lds16(Ab + (size_t)srowA * K + (kn) + scol,        &sA[nb][(w * 32) * 32]);      \
    gl_lds16(Ab + (size_t)(srowA + 16) * K + (kn) + scol, &sA[nb][(w * 32 + 16) * 32]); \
    gl_lds16(Bb + (size_t)srowB * K + (kn) + scol,        &sB[nb][(w * 16) * 32]);      \
  } while (0)

  OUT_STAGE(0, 0);
  OUT_STAGE(32, 1);

  int bi = 0;
  for (int k0 = 0; k0 < K; k0 += 32) {
    if (k0 + 64 < K) vm_wait3(); else vm_drain();
    __syncthreads();
    if (k0 + 64 < K) {
      int nb = bi + 2; if (nb >= 3) nb -= 3;
      OUT_STAGE(k0 + 64, nb);
    }
    bf16x8 af[2], bfr[4];
#pragma unroll
    for (int mt = 0; mt < 2; mt++)
      af[mt] = *(const bf16x8*)&sA[bi][(w * 32 + mt * 16 + l15) * 32 + ((quad ^ rsw) << 3)];
#pragma unroll
    for (int nt = 0; nt < 4; nt++)
      bfr[nt] = *(const bf16x8*)&sB[bi][(nt * 16 + l15) * 32 + ((quad ^ rsw) << 3)];
#pragma unroll
    for (int mt = 0; mt < 2; mt++)
#pragma unroll
      for (int nt = 0; nt < 4; nt++)
        acc[mt][nt] = __builtin_amdgcn_mfma_f32_16x16x32_bf16(af[mt], bfr[nt], acc[mt][nt], 0, 0, 0);
    bi = bi + 1; if (bi == 3) bi = 0;
  }
#undef OUT_STAGE

  const int m0 = tm * 128 + w * 32, c0 = tn * 64;
#pragma unroll
  for (int mt = 0; mt < 2; mt++)
#pragma unroll
    for (int nt = 0; nt < 4; nt++)
#pragma unroll
      for (int r = 0; r < 4; r++) {
        int m = m0 + mt * 16 + quad * 4 + r;
        int c = c0 + nt * 16 + l15;
        out[(size_t)m * 1024 + c] = acc[mt][nt][r] + bias[c];
      }
}

extern "C" void kernel_launch(void* const* d_in, const int* in_sizes, int n_in,
                              void* d_out, int out_size, void* d_ws, size_t ws_size,
                              hipStream_t stream) {
  const float* x    = (const float*)d_in[0];
  const float* Wqkv = (const float*)d_in[1];
  const float* ab   = (const float*)d_in[2];
  // d_in[3] (bias_idxs) unused: idx == |n/32-m/32|*32 + |n%32-m%32| analytically
  const float* Wout = (const float*)d_in[4];
  const float* bout = (const float*)d_in[5];
  float* out = (float*)d_out;

  char* ws = (char*)d_ws;
  unsigned short* xb  = (unsigned short*)(ws);                    // 16 MB
  unsigned short* wqb = (unsigned short*)(ws + 16777216);         // 6 MB
  unsigned short* wob = (unsigned short*)(ws + 23068672);         // 2 MB
  unsigned short* qw  = (unsigned short*)(ws + 25165824);         // 16 MB
  unsigned short* kw  = (unsigned short*)(ws + 41943040);         // 16 MB
  unsigned short* vw  = (unsigned short*)(ws + 58720256);         // 16 MB (vT)
  unsigned short* ow  = (unsigned short*)(ws + 75497472);         // 16 MB

  cast3_kernel<<<1536, 256, 0, stream>>>(x, Wqkv, Wout, xb, wqb, wob);
  gemm_qkv<<<1536, 256, 0, stream>>>(xb, wqb, qw, kw, vw);
  attn_kernel<<<512, 256, 0, stream>>>(qw, kw, vw, ab, ow);
  gemm_out_k<<<1024, 256, 0, stream>>>(ow, wob, bout, out);
}